// Round 7
// baseline (593.234 us; speedup 1.0000x reference)
//
#include <hip/hip_runtime.h>
#include <stdint.h>

// Problem constants
#define BB 4
#define LLEN 2048
#define DMODEL 2048
#define NH 24
#define DH 64
#define SS 64
#define DI 1536          // NH*DH
#define N2 3072          // 2*DI
#define NP 3096          // NH*(1+2*S)
#define NP_PAD 3200      // weight rows padded (zero rows 3096..3199); also xp ldc
#define MROWS 8192       // BB*LLEN
#define NCHUNK 16
#define QC 128           // chunk length

using bf16x8 = __bf16 __attribute__((ext_vector_type(8)));
using f32x4  = float __attribute__((ext_vector_type(4)));

__device__ __forceinline__ unsigned short f2bf(float f) {
  union { float f; unsigned int u; } v; v.f = f;
  unsigned int u = v.u + 0x7fffu + ((v.u >> 16) & 1u);
  return (unsigned short)(u >> 16);
}
__device__ __forceinline__ float bf2f(unsigned short h) {
  union { unsigned int u; float f; } v; v.u = ((unsigned int)h) << 16;
  return v.f;
}

__device__ __forceinline__ void gload16(const void* g, void* l) {
  __builtin_amdgcn_global_load_lds(
    reinterpret_cast<const __attribute__((address_space(1))) void*>(reinterpret_cast<uintptr_t>(g)),
    reinterpret_cast<__attribute__((address_space(3))) void*>((uint32_t)(reinterpret_cast<uintptr_t>(l))),
    16, 0, 0);
}

// ---------------- fp32 -> bf16 weight convert (with zero row padding) ----------
__global__ __launch_bounds__(256) void k_w2bf(const float* __restrict__ s,
                                              unsigned short* __restrict__ d,
                                              int n_src, int n_dst) {
  int i = blockIdx.x * 256 + threadIdx.x;
  if (i < n_dst) d[i] = (i < n_src) ? f2bf(s[i]) : (unsigned short)0;
}

// ---------------- RMSNorm -> bf16 ----------------
__global__ __launch_bounds__(256) void k_rmsnorm(const float* __restrict__ hs,
                                                 const float* __restrict__ w,
                                                 unsigned short* __restrict__ out) {
  const int row = blockIdx.x;
  const int t = threadIdx.x;
  const float* x = hs + (size_t)row * DMODEL;
  float4 v0 = reinterpret_cast<const float4*>(x)[t * 2 + 0];
  float4 v1 = reinterpret_cast<const float4*>(x)[t * 2 + 1];
  float ss = v0.x * v0.x + v0.y * v0.y + v0.z * v0.z + v0.w * v0.w +
             v1.x * v1.x + v1.y * v1.y + v1.z * v1.z + v1.w * v1.w;
#pragma unroll
  for (int o = 32; o; o >>= 1) ss += __shfl_xor(ss, o);
  __shared__ float red[4];
  if ((t & 63) == 0) red[t >> 6] = ss;
  __syncthreads();
  ss = red[0] + red[1] + red[2] + red[3];
  const float r = rsqrtf(ss * (1.0f / DMODEL) + 1.1920928955078125e-07f);
  float4 w0 = reinterpret_cast<const float4*>(w)[t * 2 + 0];
  float4 w1 = reinterpret_cast<const float4*>(w)[t * 2 + 1];
  union { unsigned short u[8]; uint4 v; } pk;
  pk.u[0] = f2bf(v0.x * r * w0.x); pk.u[1] = f2bf(v0.y * r * w0.y);
  pk.u[2] = f2bf(v0.z * r * w0.z); pk.u[3] = f2bf(v0.w * r * w0.w);
  pk.u[4] = f2bf(v1.x * r * w1.x); pk.u[5] = f2bf(v1.y * r * w1.y);
  pk.u[6] = f2bf(v1.z * r * w1.z); pk.u[7] = f2bf(v1.w * r * w1.w);
  *reinterpret_cast<uint4*>(out + (size_t)row * DMODEL + t * 8) = pk.v;
}

// ---------------- 8-phase 256x256 bf16 NT GEMM ---------------------------------
// EPI 0: fp32 C = acc+bias. EPI 1: bf16 C = acc+bias. EPI 2: fp32 C = resid+rg*(acc+bias).
template <int EPI>
__global__ __launch_bounds__(512, 2)
void k_gemm3(const unsigned short* __restrict__ A, const unsigned short* __restrict__ B,
             const float* __restrict__ bias, void* __restrict__ Cv,
             const float* __restrict__ resid, const float* __restrict__ gatep,
             int K, int NT_N, int Nout, int ldc) {
  __shared__ alignas(16) unsigned short sm[65536];  // 128 KB
  const int tid = threadIdx.x;
  const int lane = tid & 63, wid = tid >> 6;
  const int wm = wid >> 2, wn = wid & 3;
  const int fr = lane & 15, kg = lane >> 4;
  const int nwg = gridDim.x;
  const int wg = ((int)blockIdx.x & 7) * (nwg >> 3) + ((int)blockIdx.x >> 3);
  const int m0 = (wg / NT_N) * 256, n0 = (wg % NT_N) * 256;
  const int NI = K >> 7;   // iters; 2 K-tiles (BK=64) per iter

  const unsigned short* asrc[4];
  const unsigned short* bsrc[4];
#pragma unroll
  for (int li = 0; li < 4; ++li) {
    const int gi = li * 512 + tid, r = gi >> 3, q = gi & 7;
    asrc[li] = A + (size_t)(m0 + r) * K + ((q ^ (r & 7)) << 3);
    bsrc[li] = B + (size_t)(n0 + r) * K + ((q ^ (r & 7)) << 3);
  }
  const int wlds = wid * 64;

#define STG_A(buf, h, ko)                                                     \
  { unsigned short* d_ = sm + (buf) * 32768;                                  \
    gload16(asrc[(h)*2 + 0] + (ko), d_ + ((((h)*2 + 0) * 512 + wlds) << 3));  \
    gload16(asrc[(h)*2 + 1] + (ko), d_ + ((((h)*2 + 1) * 512 + wlds) << 3)); }
#define STG_B(buf, h, ko)                                                     \
  { unsigned short* d_ = sm + (buf) * 32768 + 16384;                          \
    gload16(bsrc[(h)*2 + 0] + (ko), d_ + ((((h)*2 + 0) * 512 + wlds) << 3));  \
    gload16(bsrc[(h)*2 + 1] + (ko), d_ + ((((h)*2 + 1) * 512 + wlds) << 3)); }

  f32x4 acc[8][4] = {};

  STG_B(0, 0, 0) STG_B(0, 1, 0) STG_A(0, 0, 0) STG_A(0, 1, 0)
  STG_B(1, 0, 64) STG_B(1, 1, 64) STG_A(1, 0, 64)
  asm volatile("s_waitcnt vmcnt(6)" ::: "memory");
  __builtin_amdgcn_s_barrier();

  bf16x8 bfv[4][2], af[2][2];
#define ARD(buf, f, kk)                                                        \
  (*(const bf16x8*)(sm + (buf) * 32768 +                                      \
      (((f) < 4 ? wm * 64 + (f) * 16 : 128 + wm * 64 + ((f) - 4) * 16) + fr) * 64 + \
      ((((kk) * 4 + kg) ^ (fr & 7)) << 3)))
#define BRD(buf, nf, kk)                                                       \
  (*(const bf16x8*)(sm + (buf) * 32768 + 16384 + (wn * 64 + (nf) * 16 + fr) * 64 + \
      ((((kk) * 4 + kg) ^ (fr & 7)) << 3)))
#define MFMA16(sp)                                                             \
  __builtin_amdgcn_s_setprio(1);                                              \
  _Pragma("unroll") for (int mf = 0; mf < 2; ++mf)                             \
  _Pragma("unroll") for (int nf = 0; nf < 4; ++nf)                            \
  _Pragma("unroll") for (int kk = 0; kk < 2; ++kk)                            \
    acc[(sp)*2 + mf][nf] = __builtin_amdgcn_mfma_f32_16x16x32_bf16(           \
        af[mf][kk], bfv[nf][kk], acc[(sp)*2 + mf][nf], 0, 0, 0);              \
  __builtin_amdgcn_s_setprio(0);

  for (int i = 0; i < NI; ++i) {
    const bool nx = (i + 1 < NI);
    const int ko1 = (2 * i + 1) << 6, ko2 = (2 * i + 2) << 6, ko3 = (2 * i + 3) << 6;

#pragma unroll
    for (int nf = 0; nf < 4; ++nf) { bfv[nf][0] = BRD(0, nf, 0); bfv[nf][1] = BRD(0, nf, 1); }
    af[0][0] = ARD(0, 0, 0); af[0][1] = ARD(0, 0, 1);
    af[1][0] = ARD(0, 1, 0); af[1][1] = ARD(0, 1, 1);
    STG_A(1, 1, ko1)
    __builtin_amdgcn_s_barrier();
    asm volatile("s_waitcnt lgkmcnt(0)" ::: "memory");
    MFMA16(0)
    __builtin_amdgcn_s_barrier();
    af[0][0] = ARD(0, 2, 0); af[0][1] = ARD(0, 2, 1);
    af[1][0] = ARD(0, 3, 0); af[1][1] = ARD(0, 3, 1);
    if (nx) STG_B(0, 0, ko2)
    __builtin_amdgcn_s_barrier();
    asm volatile("s_waitcnt lgkmcnt(0)" ::: "memory");
    MFMA16(1)
    __builtin_amdgcn_s_barrier();
    af[0][0] = ARD(0, 4, 0); af[0][1] = ARD(0, 4, 1);
    af[1][0] = ARD(0, 5, 0); af[1][1] = ARD(0, 5, 1);
    if (nx) STG_B(0, 1, ko2)
    __builtin_amdgcn_s_barrier();
    asm volatile("s_waitcnt lgkmcnt(0)" ::: "memory");
    MFMA16(2)
    __builtin_amdgcn_s_barrier();
    af[0][0] = ARD(0, 6, 0); af[0][1] = ARD(0, 6, 1);
    af[1][0] = ARD(0, 7, 0); af[1][1] = ARD(0, 7, 1);
    if (nx) STG_A(0, 0, ko2)
    __builtin_amdgcn_s_barrier();
    asm volatile("s_waitcnt lgkmcnt(0)" ::: "memory");
    MFMA16(3)
    if (nx) { asm volatile("s_waitcnt vmcnt(6)" ::: "memory"); }
    else    { asm volatile("s_waitcnt vmcnt(0)" ::: "memory"); }
    __builtin_amdgcn_s_barrier();

#pragma unroll
    for (int nf = 0; nf < 4; ++nf) { bfv[nf][0] = BRD(1, nf, 0); bfv[nf][1] = BRD(1, nf, 1); }
    af[0][0] = ARD(1, 0, 0); af[0][1] = ARD(1, 0, 1);
    af[1][0] = ARD(1, 1, 0); af[1][1] = ARD(1, 1, 1);
    if (nx) STG_A(0, 1, ko2)
    __builtin_amdgcn_s_barrier();
    asm volatile("s_waitcnt lgkmcnt(0)" ::: "memory");
    MFMA16(0)
    __builtin_amdgcn_s_barrier();
    af[0][0] = ARD(1, 2, 0); af[0][1] = ARD(1, 2, 1);
    af[1][0] = ARD(1, 3, 0); af[1][1] = ARD(1, 3, 1);
    if (nx) STG_B(1, 0, ko3)
    __builtin_amdgcn_s_barrier();
    asm volatile("s_waitcnt lgkmcnt(0)" ::: "memory");
    MFMA16(1)
    __builtin_amdgcn_s_barrier();
    af[0][0] = ARD(1, 4, 0); af[0][1] = ARD(1, 4, 1);
    af[1][0] = ARD(1, 5, 0); af[1][1] = ARD(1, 5, 1);
    if (nx) STG_B(1, 1, ko3)
    __builtin_amdgcn_s_barrier();
    asm volatile("s_waitcnt lgkmcnt(0)" ::: "memory");
    MFMA16(2)
    __builtin_amdgcn_s_barrier();
    af[0][0] = ARD(1, 6, 0); af[0][1] = ARD(1, 6, 1);
    af[1][0] = ARD(1, 7, 0); af[1][1] = ARD(1, 7, 1);
    if (nx) STG_A(1, 0, ko3)
    __builtin_amdgcn_s_barrier();
    asm volatile("s_waitcnt lgkmcnt(0)" ::: "memory");
    MFMA16(3)
    if (nx) { asm volatile("s_waitcnt vmcnt(6)" ::: "memory"); }
    __builtin_amdgcn_s_barrier();
  }

  // epilogue
  float* Cf = (float*)Cv;
  unsigned short* Ch = (unsigned short*)Cv;
  const float rg = (EPI == 2) ? gatep[0] : 0.f;
#pragma unroll
  for (int nf = 0; nf < 4; ++nf) {
    const int col = n0 + wn * 64 + nf * 16 + fr;
    if (col >= Nout) continue;
    const float bv = bias[col];
#pragma unroll
    for (int mf = 0; mf < 8; ++mf) {
      const int rowb = m0 + ((mf < 4) ? wm * 64 + mf * 16
                                      : 128 + wm * 64 + (mf - 4) * 16) + kg * 4;
#pragma unroll
      for (int r = 0; r < 4; ++r) {
        const size_t o = (size_t)(rowb + r) * ldc + col;
        float v = acc[mf][nf][r] + bv;
        if (EPI == 1) {
          Ch[o] = f2bf(v);
        } else {
          if (EPI == 2) v = resid[o] + rg * v;
          Cf[o] = v;
        }
      }
    }
  }
#undef STG_A
#undef STG_B
#undef ARD
#undef BRD
#undef MFMA16
}

// ---------------- depthwise causal conv(4) + silu, bf16 in/out, 8 ch/thread ----
__global__ __launch_bounds__(256) void k_dwconv(const unsigned short* __restrict__ xz,
                                                const float* __restrict__ cw,
                                                const float* __restrict__ cb,
                                                unsigned short* __restrict__ out) {
  const int idx = blockIdx.x * 256 + threadIdx.x;  // < MROWS*192
  const int c0 = (idx % 192) * 8;
  const int bl = idx / 192;
  const int lpos = bl & (LLEN - 1);
  float acc[8];
  const float4 cb0 = *(const float4*)(cb + c0);
  const float4 cb1 = *(const float4*)(cb + c0 + 4);
  acc[0] = cb0.x; acc[1] = cb0.y; acc[2] = cb0.z; acc[3] = cb0.w;
  acc[4] = cb1.x; acc[5] = cb1.y; acc[6] = cb1.z; acc[7] = cb1.w;
#pragma unroll
  for (int k = 0; k < 4; ++k) {
    const int ll = lpos - 3 + k;
    if (ll >= 0) {
      const uint4 xv = *(const uint4*)(xz + (size_t)(bl - 3 + k) * N2 + c0);
      const unsigned short* xs = (const unsigned short*)&xv;
#pragma unroll
      for (int j = 0; j < 8; ++j)
        acc[j] = fmaf(cw[(c0 + j) * 4 + k], bf2f(xs[j]), acc[j]);
    }
  }
  union { unsigned short u[8]; uint4 v; } pk;
#pragma unroll
  for (int j = 0; j < 8; ++j) {
    const float s = acc[j] / (1.f + __expf(-acc[j]));
    pk.u[j] = f2bf(s);
  }
  *(uint4*)(out + (size_t)bl * DI + c0) = pk.v;
}

// ---------------- prep: read bf16 xp, write normalized B/C to Bn/Cn, alpha -----
__global__ __launch_bounds__(256) void k_prep(const unsigned short* __restrict__ xp,
                                              const unsigned short* __restrict__ xc,
                                              const float* __restrict__ A_log,
                                              const float* __restrict__ l2ab,
                                              const float* __restrict__ l2b,
                                              const float* __restrict__ se,
                                              unsigned short* __restrict__ Bn,
                                              unsigned short* __restrict__ Cn,
                                              float* __restrict__ al) {
  const int blk = blockIdx.x;               // MROWS*6
  const int w = threadIdx.x >> 6, lane = threadIdx.x & 63;
  const int bl = blk / 6, hq = blk % 6;
  const int h = hq * 4 + w;
  const size_t pbase = (size_t)bl * NP_PAD + h * 129;
  const float bs = bf2f(xp[pbase + 1 + lane]);
  const float cs = bf2f(xp[pbase + 65 + lane]);
  const float xv = bf2f(xc[(size_t)bl * DI + h * DH + lane]);
  float sb = bs * bs, sc = cs * cs, sx = xv;
#pragma unroll
  for (int o = 32; o; o >>= 1) {
    sb += __shfl_xor(sb, o);
    sc += __shfl_xor(sc, o);
    sx += __shfl_xor(sx, o);
  }
  const float nb = fmaxf(sqrtf(sb), 1e-12f);
  const float nc = fmaxf(sqrtf(sc), 1e-12f);
  const int b = bl >> 11, l = bl & (LLEN - 1);
  const size_t ob = (((size_t)(b * NH + h) << 11) + l) * 64 + lane;
  Bn[ob] = f2bf(bs / nb);
  Cn[ob] = f2bf(cs / nc);
  const float sumB2 = sb / (nb * nb);
  const float xmean = sx * (1.f / 64.f);
  const float dt = bf2f(xp[pbase]);
  const float sp = (dt > 20.f) ? dt : log1pf(expf(dt));
  const float Ac = fminf(fmaxf(A_log[h], -2.3f), -0.01f);
  const float aa = expf(Ac * sp);
  const float one_a = 1.f - aa;
  const float pe = one_a * one_a * xmean * xmean * sumB2 * (1.f / 64.f);
  const float ns = pe / (se[h] + 1e-6f);
  const float beta = exp2f(fminf(fmaxf(l2b[h], -2.f), 2.f));
  const float boost = fmaxf(tanhf(beta * ns), 0.f);
  const float ab = 1.f - exp2f(fminf(fmaxf(l2ab[h], -3.32f), -0.015f));
  const float alpha = fminf(fmaxf(ab + (1.f - ab) * boost, 0.01f), 0.999f);
  if (lane == 0) al[(((size_t)b * NH + h) << 11) + l] = alpha;
}

// ---------------- chunked scan, stage 1: intra-chunk Y + local state -----------
__global__ __launch_bounds__(256) void k_chunk1(
    const unsigned short* __restrict__ Bn, const unsigned short* __restrict__ Cn,
    const unsigned short* __restrict__ xcg, const float* __restrict__ al,
    unsigned short* __restrict__ xz, unsigned short* __restrict__ Hbuf,
    float* __restrict__ Dc) {
  const int blk = blockIdx.x;          // bh*16 + c
  const int bh = blk >> 4, c = blk & 15;
  const int b = bh / NH, h = bh % NH;
  const int tid = threadIdx.x, w = tid >> 6, lane = tid & 63;
  const int fr = lane & 15, kg = lane >> 4;
  const int rbase = b * LLEN + c * QC;
  const size_t bcb = (((size_t)bh << 11) + c * QC) * 64;  // Bn/Cn base

  __shared__ float lc[QC], ia[QC], escl[QC];
  __shared__ float wtot[2];
  __shared__ alignas(16) unsigned short XT[64][152];   // [d][u]
  __shared__ alignas(16) unsigned short BsT[64][152];  // [s][u] (scaled)
  __shared__ alignas(16) unsigned short Pt[128][88];   // [t][u-local]

  float a = 1.f, la = 0.f;
  if (tid < QC) { a = al[(size_t)bh * LLEN + c * QC + tid]; la = __logf(a); }
  float s = la;
#pragma unroll
  for (int o = 1; o < 64; o <<= 1) { float t2 = __shfl_up(s, o); if (lane >= o) s += t2; }
  if (tid < QC && lane == 63) wtot[w] = s;
  __syncthreads();
  if (tid < QC) { lc[tid] = s + ((w == 1) ? wtot[0] : 0.f); ia[tid] = 1.f - a; }
  __syncthreads();
  const float lcE = lc[QC - 1];
  if (tid < QC) escl[tid] = __expf(lcE - lc[tid]) * ia[tid];
  if (tid == 0) Dc[blk] = __expf(lcE);
  __syncthreads();

  {
    const int r8 = tid >> 3, q8 = tid & 7;
#pragma unroll
    for (int it = 0; it < 4; ++it) {
      const int u = it * 32 + r8;
      const uint4 xv = *(const uint4*)(xcg + (size_t)(rbase + u) * DI + h * DH + q8 * 8);
      const unsigned short* xs = (const unsigned short*)&xv;
#pragma unroll
      for (int j = 0; j < 8; ++j) XT[q8 * 8 + j][u] = xs[j];
      const uint4 bv = *(const uint4*)(Bn + bcb + (size_t)u * 64 + q8 * 8);
      const unsigned short* bsv = (const unsigned short*)&bv;
      const float e = escl[u];
#pragma unroll
      for (int j = 0; j < 8; ++j) BsT[q8 * 8 + j][u] = f2bf(bf2f(bsv[j]) * e);
    }
  }
  bf16x8 cf[2][2];
#pragma unroll
  for (int fi = 0; fi < 2; ++fi)
#pragma unroll
    for (int kk = 0; kk < 2; ++kk) {
      const int t = w * 32 + fi * 16 + fr;
      const uint4 v = *(const uint4*)(Cn + bcb + (size_t)t * 64 + kk * 32 + kg * 8);
      cf[fi][kk] = *(const bf16x8*)&v;
    }
  __syncthreads();

  float lct[2][4];
#pragma unroll
  for (int fi = 0; fi < 2; ++fi)
#pragma unroll
    for (int r = 0; r < 4; ++r) lct[fi][r] = lc[w * 32 + fi * 16 + kg * 4 + r];

  f32x4 yacc[2][4] = {};
  f32x4 hacc[4] = {};
#pragma unroll
  for (int ut = 0; ut < 2; ++ut) {
    f32x4 g[2][4] = {};
#pragma unroll
    for (int kk = 0; kk < 2; ++kk)
#pragma unroll
      for (int fj = 0; fj < 4; ++fj) {
        const int u = ut * 64 + fj * 16 + fr;
        const uint4 v = *(const uint4*)(Bn + bcb + (size_t)u * 64 + kk * 32 + kg * 8);
        const bf16x8 bfrag = *(const bf16x8*)&v;
#pragma unroll
        for (int fi = 0; fi < 2; ++fi)
          g[fi][fj] = __builtin_amdgcn_mfma_f32_16x16x32_bf16(cf[fi][kk], bfrag, g[fi][fj], 0, 0, 0);
      }
#pragma unroll
    for (int fi = 0; fi < 2; ++fi)
#pragma unroll
      for (int fj = 0; fj < 4; ++fj) {
        const int u = ut * 64 + fj * 16 + fr;
        const float lcu = lc[u], iau = ia[u];
#pragma unroll
        for (int r = 0; r < 4; ++r) {
          const int t = w * 32 + fi * 16 + kg * 4 + r;
          const float v = (t >= u) ? g[fi][fj][r] * __expf(lct[fi][r] - lcu) * iau : 0.f;
          Pt[t][fj * 16 + fr] = f2bf(v);
        }
      }
#pragma unroll
    for (int kk = 0; kk < 2; ++kk) {
      bf16x8 xf[4];
#pragma unroll
      for (int fj = 0; fj < 4; ++fj)
        xf[fj] = *(const bf16x8*)&XT[fj * 16 + fr][ut * 64 + kk * 32 + kg * 8];
      bf16x8 pf[2];
#pragma unroll
      for (int fi = 0; fi < 2; ++fi)
        pf[fi] = *(const bf16x8*)&Pt[w * 32 + fi * 16 + fr][kk * 32 + kg * 8];
#pragma unroll
      for (int fi = 0; fi < 2; ++fi)
#pragma unroll
        for (int fj = 0; fj < 4; ++fj)
          yacc[fi][fj] = __builtin_amdgcn_mfma_f32_16x16x32_bf16(pf[fi], xf[fj], yacc[fi][fj], 0, 0, 0);
      const bf16x8 xh = *(const bf16x8*)&XT[w * 16 + fr][ut * 64 + kk * 32 + kg * 8];
#pragma unroll
      for (int fi = 0; fi < 4; ++fi) {
        const bf16x8 bs = *(const bf16x8*)&BsT[fi * 16 + fr][ut * 64 + kk * 32 + kg * 8];
        hacc[fi] = __builtin_amdgcn_mfma_f32_16x16x32_bf16(bs, xh, hacc[fi], 0, 0, 0);
      }
    }
  }
  // Y_intra -> bf16 into xz x-half
#pragma unroll
  for (int fi = 0; fi < 2; ++fi)
#pragma unroll
    for (int fj = 0; fj < 4; ++fj)
#pragma unroll
      for (int r = 0; r < 4; ++r) {
        const int t = w * 32 + fi * 16 + kg * 4 + r;
        const int d = fj * 16 + fr;
        xz[(size_t)(rbase + t) * N2 + h * DH + d] = f2bf(yacc[fi][fj][r]);
      }
  const int dcol = w * 16 + fr;
#pragma unroll
  for (int fi = 0; fi < 4; ++fi) {
    ushort4 pk;
    pk.x = f2bf(hacc[fi][0]); pk.y = f2bf(hacc[fi][1]);
    pk.z = f2bf(hacc[fi][2]); pk.w = f2bf(hacc[fi][3]);
    *(ushort4*)(Hbuf + ((size_t)blk * 64 + dcol) * 64 + fi * 16 + kg * 4) = pk;
  }
}

// ---------------- chunked scan, stage 2: carry across chunks (in place) --------
__global__ __launch_bounds__(256) void k_carry(unsigned short* __restrict__ Hbuf,
                                               const float* __restrict__ Dc) {
  const int bh = blockIdx.x, tid = threadIdx.x;
  float carry[16];
#pragma unroll
  for (int j = 0; j < 16; ++j) carry[j] = 0.f;
  for (int c = 0; c < NCHUNK; ++c) {
    unsigned short* p = Hbuf + (((size_t)(bh * NCHUNK + c)) << 12) + tid * 16;
    const uint4 v0 = *(const uint4*)(p);
    const uint4 v1 = *(const uint4*)(p + 8);
    const unsigned short* hs0 = (const unsigned short*)&v0;
    const unsigned short* hs1 = (const unsigned short*)&v1;
    float hl[16];
#pragma unroll
    for (int j = 0; j < 8; ++j) { hl[j] = bf2f(hs0[j]); hl[8 + j] = bf2f(hs1[j]); }
    uint4 o0, o1;
    unsigned short* os0 = (unsigned short*)&o0;
    unsigned short* os1 = (unsigned short*)&o1;
#pragma unroll
    for (int j = 0; j < 8; ++j) { os0[j] = f2bf(carry[j]); os1[j] = f2bf(carry[8 + j]); }
    *(uint4*)(p) = o0;
    *(uint4*)(p + 8) = o1;
    const float dc = Dc[bh * NCHUNK + c];
#pragma unroll
    for (int j = 0; j < 16; ++j) carry[j] = fmaf(dc, carry[j], hl[j]);
  }
}

// ---------------- chunked scan, stage 3: inter-chunk Y + fused gating ----------
__global__ __launch_bounds__(256) void k_chunk2(
    const unsigned short* __restrict__ Cn, const float* __restrict__ al,
    const unsigned short* __restrict__ Hbuf, const unsigned short* __restrict__ xz,
    unsigned short* __restrict__ xcg) {
  const int blk = blockIdx.x;
  const int bh = blk >> 4, c = blk & 15;
  const int b = bh / NH, h = bh % NH;
  const int tid = threadIdx.x, w = tid >> 6, lane = tid & 63;
  const int fr = lane & 15, kg = lane >> 4;
  const int rbase = b * LLEN + c * QC;
  const size_t bcb = (((size_t)bh << 11) + c * QC) * 64;
  __shared__ float lc[QC];
  __shared__ float wtot[2];
  float a = 1.f, la = 0.f;
  if (tid < QC) { a = al[(size_t)bh * LLEN + c * QC + tid]; la = __logf(a); }
  float s = la;
#pragma unroll
  for (int o = 1; o < 64; o <<= 1) { float t2 = __shfl_up(s, o); if (lane >= o) s += t2; }
  if (tid < QC && lane == 63) wtot[w] = s;
  __syncthreads();
  if (tid < QC) lc[tid] = s + ((w == 1) ? wtot[0] : 0.f);
  __syncthreads();
  bf16x8 cf[2][2];
#pragma unroll
  for (int fi = 0; fi < 2; ++fi) {
    const int t = w * 32 + fi * 16 + fr;
    const float sc = __expf(lc[t]);
#pragma unroll
    for (int kk = 0; kk < 2; ++kk) {
      const uint4 v = *(const uint4*)(Cn + bcb + (size_t)t * 64 + kk * 32 + kg * 8);
      const unsigned short* cs = (const unsigned short*)&v;
      union { unsigned short us[8]; bf16x8 vv; } uv;
#pragma unroll
      for (int q = 0; q < 8; ++q) uv.us[q] = f2bf(bf2f(cs[q]) * sc);
      cf[fi][kk] = uv.vv;
    }
  }
  bf16x8 hf[4][2];
#pragma unroll
  for (int fj = 0; fj < 4; ++fj)
#pragma unroll
    for (int kk = 0; kk < 2; ++kk) {
      const uint4 v = *(const uint4*)(Hbuf + ((size_t)blk * 64 + fj * 16 + fr) * 64 + kk * 32 + kg * 8);
      hf[fj][kk] = *(const bf16x8*)&v;
    }
  f32x4 y[2][4] = {};
#pragma unroll
  for (int kk = 0; kk < 2; ++kk)
#pragma unroll
    for (int fi = 0; fi < 2; ++fi)
#pragma unroll
      for (int fj = 0; fj < 4; ++fj)
        y[fi][fj] = __builtin_amdgcn_mfma_f32_16x16x32_bf16(cf[fi][kk], hf[fj][kk], y[fi][fj], 0, 0, 0);
#pragma unroll
  for (int fi = 0; fi < 2; ++fi)
#pragma unroll
    for (int fj = 0; fj < 4; ++fj)
#pragma unroll
      for (int r = 0; r < 4; ++r) {
        const int t = w * 32 + fi * 16 + kg * 4 + r;
        const int d = fj * 16 + fr;
        const size_t rowg = (size_t)(rbase + t);
        const float yv = y[fi][fj][r] + bf2f(xz[rowg * N2 + h * DH + d]);
        const float zv = bf2f(xz[rowg * N2 + DI + h * DH + d]);
        const float g = yv * (zv / (1.f + __expf(-zv)));
        xcg[rowg * DI + h * DH + d] = f2bf(g);
      }
}

extern "C" void kernel_launch(void* const* d_in, const int* in_sizes, int n_in,
                              void* d_out, int out_size, void* d_ws, size_t ws_size,
                              hipStream_t stream) {
  const float* hs     = (const float*)d_in[0];
  const float* norm_w = (const float*)d_in[1];
  const float* in_w   = (const float*)d_in[2];
  const float* in_b   = (const float*)d_in[3];
  const float* cw     = (const float*)d_in[4];
  const float* cb     = (const float*)d_in[5];
  const float* xw     = (const float*)d_in[6];
  const float* xb     = (const float*)d_in[7];
  const float* A_log  = (const float*)d_in[8];
  const float* l2ab   = (const float*)d_in[9];
  const float* l2b    = (const float*)d_in[10];
  const float* se     = (const float*)d_in[11];
  const float* ow     = (const float*)d_in[12];
  const float* ob     = (const float*)d_in[13];
  const float* rg     = (const float*)d_in[14];
  float* out = (float*)d_out;

  char* ws = (char*)d_ws;
  // layout (all bf16 intermediates; ~215 MB total):
  //   0          xnorm / xcg bf16 (33.5 MB)
  //   33554432   wA bf16 (12.58 MB) -> Hbuf after in_proj
  //   46137344   wX bf16 (9.83 MB)  -> al (0.79 MB) + Dc (6 KB) after x_proj
  //   55967744   wO bf16 (6.29 MB)
  //   62259200   xz bf16 8192x3072 (50.3 MB; x-half reused for Y_intra)
  //   112590848  xp bf16 8192x3200 (52.4 MB)
  //   165019648  Bn bf16 (25.2 MB)
  //   190185472  Cn bf16 (25.2 MB)
  unsigned short* xnorm = (unsigned short*)(ws);
  unsigned short* wA    = (unsigned short*)(ws + 33554432ull);
  unsigned short* wX    = (unsigned short*)(ws + 46137344ull);
  unsigned short* wO    = (unsigned short*)(ws + 55967744ull);
  unsigned short* xz    = (unsigned short*)(ws + 62259200ull);
  unsigned short* xp    = (unsigned short*)(ws + 112590848ull);
  unsigned short* Bn    = (unsigned short*)(ws + 165019648ull);
  unsigned short* Cn    = (unsigned short*)(ws + 190185472ull);
  unsigned short* xcg   = xnorm;
  unsigned short* Hbuf  = wA;
  float* al             = (float*)(ws + 46137344ull);
  float* Dc             = (float*)(ws + 46137344ull + 786432ull);

  k_w2bf<<<(N2 * DMODEL) / 256, 256, 0, stream>>>(in_w, wA, N2 * DMODEL, N2 * DMODEL);
  k_w2bf<<<(NP_PAD * DI) / 256, 256, 0, stream>>>(xw, wX, NP * DI, NP_PAD * DI);
  k_w2bf<<<(DMODEL * DI) / 256, 256, 0, stream>>>(ow, wO, DMODEL * DI, DMODEL * DI);

  k_rmsnorm<<<MROWS, 256, 0, stream>>>(hs, norm_w, xnorm);
  // in_proj: 32 x 12 = 384 blocks, bf16 out
  k_gemm3<1><<<384, 512, 0, stream>>>(xnorm, wA, in_b, xz, nullptr, nullptr,
                                      DMODEL, 12, N2, N2);
  k_dwconv<<<(MROWS * 192) / 256, 256, 0, stream>>>(xz, cw, cb, xcg);
  // x_proj: 32 x 13 = 416 blocks, bf16 out, ldc padded to 3200
  k_gemm3<1><<<416, 512, 0, stream>>>(xcg, wX, xb, xp, nullptr, nullptr,
                                      DI, 13, NP, NP_PAD);
  k_prep<<<MROWS * 6, 256, 0, stream>>>(xp, xcg, A_log, l2ab, l2b, se, Bn, Cn, al);

  k_chunk1<<<BB * NH * NCHUNK, 256, 0, stream>>>(Bn, Cn, xcg, al, xz, Hbuf, Dc);
  k_carry<<<BB * NH, 256, 0, stream>>>(Hbuf, Dc);
  k_chunk2<<<BB * NH * NCHUNK, 256, 0, stream>>>(Cn, al, Hbuf, xz, xcg);

  // out_proj: 32 x 8 = 256 blocks, fp32 + residual
  k_gemm3<2><<<256, 512, 0, stream>>>(xcg, wO, ob, out, hs, rg,
                                      DI, 8, DMODEL, DMODEL);
}

// Round 8
// 524.218 us; speedup vs baseline: 1.1317x; 1.1317x over previous
//
#include <hip/hip_runtime.h>
#include <stdint.h>

// Problem constants
#define BB 4
#define LLEN 2048
#define DMODEL 2048
#define NH 24
#define DH 64
#define SS 64
#define DI 1536          // NH*DH
#define N2 3072          // 2*DI
#define NP 3096          // NH*(1+2*S)
#define NP_PAD 3200      // weight rows padded (zero rows 3096..3199); also xp ldc
#define MROWS 8192       // BB*LLEN
#define NCHUNK 16
#define QC 128           // chunk length

using bf16x8 = __bf16 __attribute__((ext_vector_type(8)));
using f32x4  = float __attribute__((ext_vector_type(4)));

__device__ __forceinline__ unsigned short f2bf(float f) {
  union { float f; unsigned int u; } v; v.f = f;
  unsigned int u = v.u + 0x7fffu + ((v.u >> 16) & 1u);
  return (unsigned short)(u >> 16);
}
__device__ __forceinline__ float bf2f(unsigned short h) {
  union { unsigned int u; float f; } v; v.u = ((unsigned int)h) << 16;
  return v.f;
}

__device__ __forceinline__ void gload16(const void* g, void* l) {
  __builtin_amdgcn_global_load_lds(
    reinterpret_cast<const __attribute__((address_space(1))) void*>(reinterpret_cast<uintptr_t>(g)),
    reinterpret_cast<__attribute__((address_space(3))) void*>((uint32_t)(reinterpret_cast<uintptr_t>(l))),
    16, 0, 0);
}

// ---------------- fp32 -> bf16 weight convert (with zero row padding) ----------
__global__ __launch_bounds__(256) void k_w2bf(const float* __restrict__ s,
                                              unsigned short* __restrict__ d,
                                              int n_src, int n_dst) {
  int i = blockIdx.x * 256 + threadIdx.x;
  if (i < n_dst) d[i] = (i < n_src) ? f2bf(s[i]) : (unsigned short)0;
}

// ---------------- RMSNorm -> bf16 ----------------
__global__ __launch_bounds__(256) void k_rmsnorm(const float* __restrict__ hs,
                                                 const float* __restrict__ w,
                                                 unsigned short* __restrict__ out) {
  const int row = blockIdx.x;
  const int t = threadIdx.x;
  const float* x = hs + (size_t)row * DMODEL;
  float4 v0 = reinterpret_cast<const float4*>(x)[t * 2 + 0];
  float4 v1 = reinterpret_cast<const float4*>(x)[t * 2 + 1];
  float ss = v0.x * v0.x + v0.y * v0.y + v0.z * v0.z + v0.w * v0.w +
             v1.x * v1.x + v1.y * v1.y + v1.z * v1.z + v1.w * v1.w;
#pragma unroll
  for (int o = 32; o; o >>= 1) ss += __shfl_xor(ss, o);
  __shared__ float red[4];
  if ((t & 63) == 0) red[t >> 6] = ss;
  __syncthreads();
  ss = red[0] + red[1] + red[2] + red[3];
  const float r = rsqrtf(ss * (1.0f / DMODEL) + 1.1920928955078125e-07f);
  float4 w0 = reinterpret_cast<const float4*>(w)[t * 2 + 0];
  float4 w1 = reinterpret_cast<const float4*>(w)[t * 2 + 1];
  union { unsigned short u[8]; uint4 v; } pk;
  pk.u[0] = f2bf(v0.x * r * w0.x); pk.u[1] = f2bf(v0.y * r * w0.y);
  pk.u[2] = f2bf(v0.z * r * w0.z); pk.u[3] = f2bf(v0.w * r * w0.w);
  pk.u[4] = f2bf(v1.x * r * w1.x); pk.u[5] = f2bf(v1.y * r * w1.y);
  pk.u[6] = f2bf(v1.z * r * w1.z); pk.u[7] = f2bf(v1.w * r * w1.w);
  *reinterpret_cast<uint4*>(out + (size_t)row * DMODEL + t * 8) = pk.v;
}

// ---------------- 8-phase 256x256 bf16 NT GEMM ---------------------------------
// EPI 1: bf16 C = acc+bias. EPI 2: fp32 C = resid + rg*(acc+bias).
template <int EPI>
__global__ __launch_bounds__(512, 2)
void k_gemm3(const unsigned short* __restrict__ A, const unsigned short* __restrict__ B,
             const float* __restrict__ bias, void* __restrict__ Cv,
             const float* __restrict__ resid, const float* __restrict__ gatep,
             int K, int NT_N, int Nout, int ldc) {
  __shared__ alignas(16) unsigned short sm[65536];  // 128 KB
  const int tid = threadIdx.x;
  const int lane = tid & 63, wid = tid >> 6;
  const int wm = wid >> 2, wn = wid & 3;
  const int fr = lane & 15, kg = lane >> 4;
  const int nwg = gridDim.x;
  const int wg = ((int)blockIdx.x & 7) * (nwg >> 3) + ((int)blockIdx.x >> 3);
  const int m0 = (wg / NT_N) * 256, n0 = (wg % NT_N) * 256;
  const int NI = K >> 7;   // iters; 2 K-tiles (BK=64) per iter

  const unsigned short* asrc[4];
  const unsigned short* bsrc[4];
#pragma unroll
  for (int li = 0; li < 4; ++li) {
    const int gi = li * 512 + tid, r = gi >> 3, q = gi & 7;
    asrc[li] = A + (size_t)(m0 + r) * K + ((q ^ (r & 7)) << 3);
    bsrc[li] = B + (size_t)(n0 + r) * K + ((q ^ (r & 7)) << 3);
  }
  const int wlds = wid * 64;

#define STG_A(buf, h, ko)                                                     \
  { unsigned short* d_ = sm + (buf) * 32768;                                  \
    gload16(asrc[(h)*2 + 0] + (ko), d_ + ((((h)*2 + 0) * 512 + wlds) << 3));  \
    gload16(asrc[(h)*2 + 1] + (ko), d_ + ((((h)*2 + 1) * 512 + wlds) << 3)); }
#define STG_B(buf, h, ko)                                                     \
  { unsigned short* d_ = sm + (buf) * 32768 + 16384;                          \
    gload16(bsrc[(h)*2 + 0] + (ko), d_ + ((((h)*2 + 0) * 512 + wlds) << 3));  \
    gload16(bsrc[(h)*2 + 1] + (ko), d_ + ((((h)*2 + 1) * 512 + wlds) << 3)); }

  f32x4 acc[8][4] = {};

  STG_B(0, 0, 0) STG_B(0, 1, 0) STG_A(0, 0, 0) STG_A(0, 1, 0)
  STG_B(1, 0, 64) STG_B(1, 1, 64) STG_A(1, 0, 64)
  asm volatile("s_waitcnt vmcnt(6)" ::: "memory");
  __builtin_amdgcn_s_barrier();

  bf16x8 bfv[4][2], af[2][2];
#define ARD(buf, f, kk)                                                        \
  (*(const bf16x8*)(sm + (buf) * 32768 +                                      \
      (((f) < 4 ? wm * 64 + (f) * 16 : 128 + wm * 64 + ((f) - 4) * 16) + fr) * 64 + \
      ((((kk) * 4 + kg) ^ (fr & 7)) << 3)))
#define BRD(buf, nf, kk)                                                       \
  (*(const bf16x8*)(sm + (buf) * 32768 + 16384 + (wn * 64 + (nf) * 16 + fr) * 64 + \
      ((((kk) * 4 + kg) ^ (fr & 7)) << 3)))
#define MFMA16(sp)                                                             \
  __builtin_amdgcn_s_setprio(1);                                              \
  _Pragma("unroll") for (int mf = 0; mf < 2; ++mf)                             \
  _Pragma("unroll") for (int nf = 0; nf < 4; ++nf)                            \
  _Pragma("unroll") for (int kk = 0; kk < 2; ++kk)                            \
    acc[(sp)*2 + mf][nf] = __builtin_amdgcn_mfma_f32_16x16x32_bf16(           \
        af[mf][kk], bfv[nf][kk], acc[(sp)*2 + mf][nf], 0, 0, 0);              \
  __builtin_amdgcn_s_setprio(0);

  for (int i = 0; i < NI; ++i) {
    const bool nx = (i + 1 < NI);
    const int ko1 = (2 * i + 1) << 6, ko2 = (2 * i + 2) << 6, ko3 = (2 * i + 3) << 6;

#pragma unroll
    for (int nf = 0; nf < 4; ++nf) { bfv[nf][0] = BRD(0, nf, 0); bfv[nf][1] = BRD(0, nf, 1); }
    af[0][0] = ARD(0, 0, 0); af[0][1] = ARD(0, 0, 1);
    af[1][0] = ARD(0, 1, 0); af[1][1] = ARD(0, 1, 1);
    STG_A(1, 1, ko1)
    __builtin_amdgcn_s_barrier();
    asm volatile("s_waitcnt lgkmcnt(0)" ::: "memory");
    MFMA16(0)
    __builtin_amdgcn_s_barrier();
    af[0][0] = ARD(0, 2, 0); af[0][1] = ARD(0, 2, 1);
    af[1][0] = ARD(0, 3, 0); af[1][1] = ARD(0, 3, 1);
    if (nx) STG_B(0, 0, ko2)
    __builtin_amdgcn_s_barrier();
    asm volatile("s_waitcnt lgkmcnt(0)" ::: "memory");
    MFMA16(1)
    __builtin_amdgcn_s_barrier();
    af[0][0] = ARD(0, 4, 0); af[0][1] = ARD(0, 4, 1);
    af[1][0] = ARD(0, 5, 0); af[1][1] = ARD(0, 5, 1);
    if (nx) STG_B(0, 1, ko2)
    __builtin_amdgcn_s_barrier();
    asm volatile("s_waitcnt lgkmcnt(0)" ::: "memory");
    MFMA16(2)
    __builtin_amdgcn_s_barrier();
    af[0][0] = ARD(0, 6, 0); af[0][1] = ARD(0, 6, 1);
    af[1][0] = ARD(0, 7, 0); af[1][1] = ARD(0, 7, 1);
    if (nx) STG_A(0, 0, ko2)
    __builtin_amdgcn_s_barrier();
    asm volatile("s_waitcnt lgkmcnt(0)" ::: "memory");
    MFMA16(3)
    if (nx) { asm volatile("s_waitcnt vmcnt(6)" ::: "memory"); }
    else    { asm volatile("s_waitcnt vmcnt(0)" ::: "memory"); }
    __builtin_amdgcn_s_barrier();

#pragma unroll
    for (int nf = 0; nf < 4; ++nf) { bfv[nf][0] = BRD(1, nf, 0); bfv[nf][1] = BRD(1, nf, 1); }
    af[0][0] = ARD(1, 0, 0); af[0][1] = ARD(1, 0, 1);
    af[1][0] = ARD(1, 1, 0); af[1][1] = ARD(1, 1, 1);
    if (nx) STG_A(0, 1, ko2)
    __builtin_amdgcn_s_barrier();
    asm volatile("s_waitcnt lgkmcnt(0)" ::: "memory");
    MFMA16(0)
    __builtin_amdgcn_s_barrier();
    af[0][0] = ARD(1, 2, 0); af[0][1] = ARD(1, 2, 1);
    af[1][0] = ARD(1, 3, 0); af[1][1] = ARD(1, 3, 1);
    if (nx) STG_B(1, 0, ko3)
    __builtin_amdgcn_s_barrier();
    asm volatile("s_waitcnt lgkmcnt(0)" ::: "memory");
    MFMA16(1)
    __builtin_amdgcn_s_barrier();
    af[0][0] = ARD(1, 4, 0); af[0][1] = ARD(1, 4, 1);
    af[1][0] = ARD(1, 5, 0); af[1][1] = ARD(1, 5, 1);
    if (nx) STG_B(1, 1, ko3)
    __builtin_amdgcn_s_barrier();
    asm volatile("s_waitcnt lgkmcnt(0)" ::: "memory");
    MFMA16(2)
    __builtin_amdgcn_s_barrier();
    af[0][0] = ARD(1, 6, 0); af[0][1] = ARD(1, 6, 1);
    af[1][0] = ARD(1, 7, 0); af[1][1] = ARD(1, 7, 1);
    if (nx) STG_A(1, 0, ko3)
    __builtin_amdgcn_s_barrier();
    asm volatile("s_waitcnt lgkmcnt(0)" ::: "memory");
    MFMA16(3)
    if (nx) { asm volatile("s_waitcnt vmcnt(6)" ::: "memory"); }
    __builtin_amdgcn_s_barrier();
  }

  float* Cf = (float*)Cv;
  unsigned short* Ch = (unsigned short*)Cv;
  const float rg = (EPI == 2) ? gatep[0] : 0.f;
#pragma unroll
  for (int nf = 0; nf < 4; ++nf) {
    const int col = n0 + wn * 64 + nf * 16 + fr;
    if (col >= Nout) continue;
    const float bv = bias[col];
#pragma unroll
    for (int mf = 0; mf < 8; ++mf) {
      const int rowb = m0 + ((mf < 4) ? wm * 64 + mf * 16
                                      : 128 + wm * 64 + (mf - 4) * 16) + kg * 4;
#pragma unroll
      for (int r = 0; r < 4; ++r) {
        const size_t o = (size_t)(rowb + r) * ldc + col;
        float v = acc[mf][nf][r] + bv;
        if (EPI == 1) {
          Ch[o] = f2bf(v);
        } else {
          if (EPI == 2) v = resid[o] + rg * v;
          Cf[o] = v;
        }
      }
    }
  }
#undef STG_A
#undef STG_B
#undef ARD
#undef BRD
#undef MFMA16
}

// ---------------- 4-phase 128x256 bf16 NT GEMM (tail-exact grid variant) -------
// bf16 C = acc + bias. 512 thr = 8 waves (2M x 4N), per-wave 64x64.
// LDS 96KB = 2 dbuf x (A 16KB + B 32KB). BK=64, 2 K-tiles/iter, 4 phases/iter.
// Staging slots: A(t+1)@P1, B(t+2)@P2, A(t+2)@P3, B(t+3)@P4; vmcnt(4) at P2/P4.
__global__ __launch_bounds__(512, 2)
void k_gemm4(const unsigned short* __restrict__ A, const unsigned short* __restrict__ B,
             const float* __restrict__ bias, unsigned short* __restrict__ C,
             int K, int NT_N, int Nout, int ldc) {
  __shared__ alignas(16) unsigned short sm[49152];  // 96 KB
  const int tid = threadIdx.x;
  const int lane = tid & 63, wid = tid >> 6;
  const int wm = wid >> 2, wn = wid & 3;
  const int fr = lane & 15, kg = lane >> 4;
  const int nwg = gridDim.x;
  const int wg = ((int)blockIdx.x & 7) * (nwg >> 3) + ((int)blockIdx.x >> 3);
  const int m0 = (wg / NT_N) * 128, n0 = (wg % NT_N) * 256;
  const int NI = K >> 7;

  const unsigned short* asrc[2];
  const unsigned short* bsrc[4];
#pragma unroll
  for (int li = 0; li < 2; ++li) {
    const int gi = li * 512 + tid, r = gi >> 3, q = gi & 7;
    asrc[li] = A + (size_t)(m0 + r) * K + ((q ^ (r & 7)) << 3);
  }
#pragma unroll
  for (int li = 0; li < 4; ++li) {
    const int gi = li * 512 + tid, r = gi >> 3, q = gi & 7;
    bsrc[li] = B + (size_t)(n0 + r) * K + ((q ^ (r & 7)) << 3);
  }
  const int wlds = wid * 64;

#define STG_A4(buf, ko)                                                       \
  { unsigned short* d_ = sm + (buf) * 24576;                                  \
    gload16(asrc[0] + (ko), d_ + ((0 * 512 + wlds) << 3));                    \
    gload16(asrc[1] + (ko), d_ + ((1 * 512 + wlds) << 3)); }
#define STG_B4(buf, h, ko)                                                    \
  { unsigned short* d_ = sm + (buf) * 24576 + 8192;                           \
    gload16(bsrc[(h)*2 + 0] + (ko), d_ + ((((h)*2 + 0) * 512 + wlds) << 3));  \
    gload16(bsrc[(h)*2 + 1] + (ko), d_ + ((((h)*2 + 1) * 512 + wlds) << 3)); }

  f32x4 acc[4][4] = {};

  // prologue: tile0 {B,A}, tile1 {B}  (10 loads); retire tile0's 6
  STG_B4(0, 0, 0) STG_B4(0, 1, 0) STG_A4(0, 0)
  STG_B4(1, 0, 64) STG_B4(1, 1, 64)
  asm volatile("s_waitcnt vmcnt(4)" ::: "memory");
  __builtin_amdgcn_s_barrier();

  bf16x8 bfv[4][2], af[2][2];
#define ARD4(buf, mf, kk)                                                      \
  (*(const bf16x8*)(sm + (buf) * 24576 + (wm * 64 + (mf) * 16 + fr) * 64 +    \
      ((((kk) * 4 + kg) ^ (fr & 7)) << 3)))
#define BRD4(buf, nf, kk)                                                      \
  (*(const bf16x8*)(sm + (buf) * 24576 + 8192 + (wn * 64 + (nf) * 16 + fr) * 64 + \
      ((((kk) * 4 + kg) ^ (fr & 7)) << 3)))
#define MFMA16_4(p)                                                            \
  __builtin_amdgcn_s_setprio(1);                                              \
  _Pragma("unroll") for (int mf = 0; mf < 2; ++mf)                             \
  _Pragma("unroll") for (int nf = 0; nf < 4; ++nf)                            \
  _Pragma("unroll") for (int kk = 0; kk < 2; ++kk)                            \
    acc[(p)*2 + mf][nf] = __builtin_amdgcn_mfma_f32_16x16x32_bf16(            \
        af[mf][kk], bfv[nf][kk], acc[(p)*2 + mf][nf], 0, 0, 0);               \
  __builtin_amdgcn_s_setprio(0);

  for (int i = 0; i < NI; ++i) {
    const bool nx = (i + 1 < NI);
    const int ko1 = (2 * i + 1) << 6, ko2 = (2 * i + 2) << 6, ko3 = (2 * i + 3) << 6;

    // P1: read buf0 B(all)+A(mf0-1); stage A(tile 2i+1) -> buf1
#pragma unroll
    for (int nf = 0; nf < 4; ++nf) { bfv[nf][0] = BRD4(0, nf, 0); bfv[nf][1] = BRD4(0, nf, 1); }
    af[0][0] = ARD4(0, 0, 0); af[0][1] = ARD4(0, 0, 1);
    af[1][0] = ARD4(0, 1, 0); af[1][1] = ARD4(0, 1, 1);
    STG_A4(1, ko1)
    __builtin_amdgcn_s_barrier();
    asm volatile("s_waitcnt lgkmcnt(0)" ::: "memory");
    MFMA16_4(0)
    __builtin_amdgcn_s_barrier();
    // P2: read buf0 A(mf2-3); stage B(2i+2) -> buf0; retire tile(2i+1)
    af[0][0] = ARD4(0, 2, 0); af[0][1] = ARD4(0, 2, 1);
    af[1][0] = ARD4(0, 3, 0); af[1][1] = ARD4(0, 3, 1);
    if (nx) { STG_B4(0, 0, ko2) STG_B4(0, 1, ko2) }
    __builtin_amdgcn_s_barrier();
    asm volatile("s_waitcnt lgkmcnt(0)" ::: "memory");
    MFMA16_4(1)
    if (nx) { asm volatile("s_waitcnt vmcnt(4)" ::: "memory"); }
    else    { asm volatile("s_waitcnt vmcnt(0)" ::: "memory"); }
    __builtin_amdgcn_s_barrier();
    // P3: read buf1 B(all)+A(mf0-1); stage A(2i+2) -> buf0
#pragma unroll
    for (int nf = 0; nf < 4; ++nf) { bfv[nf][0] = BRD4(1, nf, 0); bfv[nf][1] = BRD4(1, nf, 1); }
    af[0][0] = ARD4(1, 0, 0); af[0][1] = ARD4(1, 0, 1);
    af[1][0] = ARD4(1, 1, 0); af[1][1] = ARD4(1, 1, 1);
    if (nx) STG_A4(0, ko2)
    __builtin_amdgcn_s_barrier();
    asm volatile("s_waitcnt lgkmcnt(0)" ::: "memory");
    MFMA16_4(0)
    __builtin_amdgcn_s_barrier();
    // P4: read buf1 A(mf2-3); stage B(2i+3) -> buf1; retire tile(2i+2)
    af[0][0] = ARD4(1, 2, 0); af[0][1] = ARD4(1, 2, 1);
    af[1][0] = ARD4(1, 3, 0); af[1][1] = ARD4(1, 3, 1);
    if (nx) { STG_B4(1, 0, ko3) STG_B4(1, 1, ko3) }
    __builtin_amdgcn_s_barrier();
    asm volatile("s_waitcnt lgkmcnt(0)" ::: "memory");
    MFMA16_4(1)
    if (nx) { asm volatile("s_waitcnt vmcnt(4)" ::: "memory"); }
    __builtin_amdgcn_s_barrier();
  }

  // epilogue: bf16 C = acc + bias
#pragma unroll
  for (int nf = 0; nf < 4; ++nf) {
    const int col = n0 + wn * 64 + nf * 16 + fr;
    if (col >= Nout) continue;
    const float bv = bias[col];
#pragma unroll
    for (int mf = 0; mf < 4; ++mf) {
      const int rowb = m0 + wm * 64 + mf * 16 + kg * 4;
#pragma unroll
      for (int r = 0; r < 4; ++r) {
        const size_t o = (size_t)(rowb + r) * ldc + col;
        C[o] = f2bf(acc[mf][nf][r] + bv);
      }
    }
  }
#undef STG_A4
#undef STG_B4
#undef ARD4
#undef BRD4
#undef MFMA16_4
}

// ---------------- depthwise causal conv(4) + silu, 4 timesteps x 8 ch/thread ---
__global__ __launch_bounds__(256) void k_dwconv(const unsigned short* __restrict__ xz,
                                                const float* __restrict__ cw,
                                                const float* __restrict__ cb,
                                                unsigned short* __restrict__ out) {
  const int idx = blockIdx.x * 256 + threadIdx.x;  // < (MROWS/4)*192
  const int c0 = (idx % 192) * 8;
  const int bl0 = (idx / 192) * 4;
  const int lpos0 = bl0 & (LLEN - 1);
  float w[8][4];
#pragma unroll
  for (int j = 0; j < 8; ++j) {
    const float4 wv = *(const float4*)(cw + (c0 + j) * 4);
    w[j][0] = wv.x; w[j][1] = wv.y; w[j][2] = wv.z; w[j][3] = wv.w;
  }
  float xr[7][8];
#pragma unroll
  for (int m = 0; m < 7; ++m) {
    uint4 xv = make_uint4(0u, 0u, 0u, 0u);
    if (lpos0 - 3 + m >= 0)
      xv = *(const uint4*)(xz + (size_t)(bl0 - 3 + m) * N2 + c0);
    const unsigned short* xs = (const unsigned short*)&xv;
#pragma unroll
    for (int j = 0; j < 8; ++j) xr[m][j] = bf2f(xs[j]);
  }
  const float4 cb0 = *(const float4*)(cb + c0);
  const float4 cb1 = *(const float4*)(cb + c0 + 4);
  const float cbv[8] = {cb0.x, cb0.y, cb0.z, cb0.w, cb1.x, cb1.y, cb1.z, cb1.w};
#pragma unroll
  for (int t4 = 0; t4 < 4; ++t4) {
    union { unsigned short u[8]; uint4 v; } pk;
#pragma unroll
    for (int j = 0; j < 8; ++j) {
      float a = cbv[j];
#pragma unroll
      for (int k = 0; k < 4; ++k) a = fmaf(w[j][k], xr[t4 + k][j], a);
      a = a / (1.f + __expf(-a));
      pk.u[j] = f2bf(a);
    }
    *(uint4*)(out + (size_t)(bl0 + t4) * DI + c0) = pk.v;
  }
}

// ---------------- prep: read bf16 xp, write normalized B/C to Bn/Cn, alpha -----
__global__ __launch_bounds__(256) void k_prep(const unsigned short* __restrict__ xp,
                                              const unsigned short* __restrict__ xc,
                                              const float* __restrict__ A_log,
                                              const float* __restrict__ l2ab,
                                              const float* __restrict__ l2b,
                                              const float* __restrict__ se,
                                              unsigned short* __restrict__ Bn,
                                              unsigned short* __restrict__ Cn,
                                              float* __restrict__ al) {
  const int blk = blockIdx.x;               // MROWS*6
  const int w = threadIdx.x >> 6, lane = threadIdx.x & 63;
  const int bl = blk / 6, hq = blk % 6;
  const int h = hq * 4 + w;
  const size_t pbase = (size_t)bl * NP_PAD + h * 129;
  const float bs = bf2f(xp[pbase + 1 + lane]);
  const float cs = bf2f(xp[pbase + 65 + lane]);
  const float xv = bf2f(xc[(size_t)bl * DI + h * DH + lane]);
  float sb = bs * bs, sc = cs * cs, sx = xv;
#pragma unroll
  for (int o = 32; o; o >>= 1) {
    sb += __shfl_xor(sb, o);
    sc += __shfl_xor(sc, o);
    sx += __shfl_xor(sx, o);
  }
  const float nb = fmaxf(sqrtf(sb), 1e-12f);
  const float nc = fmaxf(sqrtf(sc), 1e-12f);
  const int b = bl >> 11, l = bl & (LLEN - 1);
  const size_t ob = (((size_t)(b * NH + h) << 11) + l) * 64 + lane;
  Bn[ob] = f2bf(bs / nb);
  Cn[ob] = f2bf(cs / nc);
  const float sumB2 = sb / (nb * nb);
  const float xmean = sx * (1.f / 64.f);
  const float dt = bf2f(xp[pbase]);
  const float sp = (dt > 20.f) ? dt : log1pf(expf(dt));
  const float Ac = fminf(fmaxf(A_log[h], -2.3f), -0.01f);
  const float aa = expf(Ac * sp);
  const float one_a = 1.f - aa;
  const float pe = one_a * one_a * xmean * xmean * sumB2 * (1.f / 64.f);
  const float ns = pe / (se[h] + 1e-6f);
  const float beta = exp2f(fminf(fmaxf(l2b[h], -2.f), 2.f));
  const float boost = fmaxf(tanhf(beta * ns), 0.f);
  const float ab = 1.f - exp2f(fminf(fmaxf(l2ab[h], -3.32f), -0.015f));
  const float alpha = fminf(fmaxf(ab + (1.f - ab) * boost, 0.01f), 0.999f);
  if (lane == 0) al[(((size_t)b * NH + h) << 11) + l] = alpha;
}

// ---------------- chunked scan, stage 1: intra-chunk Y + local state -----------
__global__ __launch_bounds__(256) void k_chunk1(
    const unsigned short* __restrict__ Bn, const unsigned short* __restrict__ Cn,
    const unsigned short* __restrict__ xcg, const float* __restrict__ al,
    unsigned short* __restrict__ xz, unsigned short* __restrict__ Hbuf,
    float* __restrict__ Dc) {
  const int blk = blockIdx.x;          // bh*16 + c
  const int bh = blk >> 4, c = blk & 15;
  const int b = bh / NH, h = bh % NH;
  const int tid = threadIdx.x, w = tid >> 6, lane = tid & 63;
  const int fr = lane & 15, kg = lane >> 4;
  const int rbase = b * LLEN + c * QC;
  const size_t bcb = (((size_t)bh << 11) + c * QC) * 64;  // Bn/Cn base

  __shared__ float lc[QC], ia[QC], escl[QC];
  __shared__ float wtot[2];
  __shared__ alignas(16) unsigned short XT[64][152];   // [d][u]
  __shared__ alignas(16) unsigned short BsT[64][152];  // [s][u] (scaled)
  __shared__ alignas(16) unsigned short Pt[128][88];   // [t][u-local]

  float a = 1.f, la = 0.f;
  if (tid < QC) { a = al[(size_t)bh * LLEN + c * QC + tid]; la = __logf(a); }
  float s = la;
#pragma unroll
  for (int o = 1; o < 64; o <<= 1) { float t2 = __shfl_up(s, o); if (lane >= o) s += t2; }
  if (tid < QC && lane == 63) wtot[w] = s;
  __syncthreads();
  if (tid < QC) { lc[tid] = s + ((w == 1) ? wtot[0] : 0.f); ia[tid] = 1.f - a; }
  __syncthreads();
  const float lcE = lc[QC - 1];
  if (tid < QC) escl[tid] = __expf(lcE - lc[tid]) * ia[tid];
  if (tid == 0) Dc[blk] = __expf(lcE);
  __syncthreads();

  {
    const int r8 = tid >> 3, q8 = tid & 7;
#pragma unroll
    for (int it = 0; it < 4; ++it) {
      const int u = it * 32 + r8;
      const uint4 xv = *(const uint4*)(xcg + (size_t)(rbase + u) * DI + h * DH + q8 * 8);
      const unsigned short* xs = (const unsigned short*)&xv;
#pragma unroll
      for (int j = 0; j < 8; ++j) XT[q8 * 8 + j][u] = xs[j];
      const uint4 bv = *(const uint4*)(Bn + bcb + (size_t)u * 64 + q8 * 8);
      const unsigned short* bsv = (const unsigned short*)&bv;
      const float e = escl[u];
#pragma unroll
      for (int j = 0; j < 8; ++j) BsT[q8 * 8 + j][u] = f2bf(bf2f(bsv[j]) * e);
    }
  }
  bf16x8 cf[2][2];
#pragma unroll
  for (int fi = 0; fi < 2; ++fi)
#pragma unroll
    for (int kk = 0; kk < 2; ++kk) {
      const int t = w * 32 + fi * 16 + fr;
      const uint4 v = *(const uint4*)(Cn + bcb + (size_t)t * 64 + kk * 32 + kg * 8);
      cf[fi][kk] = *(const bf16x8*)&v;
    }
  __syncthreads();

  float lct[2][4];
#pragma unroll
  for (int fi = 0; fi < 2; ++fi)
#pragma unroll
    for (int r = 0; r < 4; ++r) lct[fi][r] = lc[w * 32 + fi * 16 + kg * 4 + r];

  f32x4 yacc[2][4] = {};
  f32x4 hacc[4] = {};
#pragma unroll
  for (int ut = 0; ut < 2; ++ut) {
    f32x4 g[2][4] = {};
#pragma unroll
    for (int kk = 0; kk < 2; ++kk)
#pragma unroll
      for (int fj = 0; fj < 4; ++fj) {
        const int u = ut * 64 + fj * 16 + fr;
        const uint4 v = *(const uint4*)(Bn + bcb + (size_t)u * 64 + kk * 32 + kg * 8);
        const bf16x8 bfrag = *(const bf16x8*)&v;
#pragma unroll
        for (int fi = 0; fi < 2; ++fi)
          g[fi][fj] = __builtin_amdgcn_mfma_f32_16x16x32_bf16(cf[fi][kk], bfrag, g[fi][fj], 0, 0, 0);
      }
#pragma unroll
    for (int fi = 0; fi < 2; ++fi)
#pragma unroll
      for (int fj = 0; fj < 4; ++fj) {
        const int u = ut * 64 + fj * 16 + fr;
        const float lcu = lc[u], iau = ia[u];
#pragma unroll
        for (int r = 0; r < 4; ++r) {
          const int t = w * 32 + fi * 16 + kg * 4 + r;
          const float v = (t >= u) ? g[fi][fj][r] * __expf(lct[fi][r] - lcu) * iau : 0.f;
          Pt[t][fj * 16 + fr] = f2bf(v);
        }
      }
#pragma unroll
    for (int kk = 0; kk < 2; ++kk) {
      bf16x8 xf[4];
#pragma unroll
      for (int fj = 0; fj < 4; ++fj)
        xf[fj] = *(const bf16x8*)&XT[fj * 16 + fr][ut * 64 + kk * 32 + kg * 8];
      bf16x8 pf[2];
#pragma unroll
      for (int fi = 0; fi < 2; ++fi)
        pf[fi] = *(const bf16x8*)&Pt[w * 32 + fi * 16 + fr][kk * 32 + kg * 8];
#pragma unroll
      for (int fi = 0; fi < 2; ++fi)
#pragma unroll
        for (int fj = 0; fj < 4; ++fj)
          yacc[fi][fj] = __builtin_amdgcn_mfma_f32_16x16x32_bf16(pf[fi], xf[fj], yacc[fi][fj], 0, 0, 0);
      const bf16x8 xh = *(const bf16x8*)&XT[w * 16 + fr][ut * 64 + kk * 32 + kg * 8];
#pragma unroll
      for (int fi = 0; fi < 4; ++fi) {
        const bf16x8 bs = *(const bf16x8*)&BsT[fi * 16 + fr][ut * 64 + kk * 32 + kg * 8];
        hacc[fi] = __builtin_amdgcn_mfma_f32_16x16x32_bf16(bs, xh, hacc[fi], 0, 0, 0);
      }
    }
  }
#pragma unroll
  for (int fi = 0; fi < 2; ++fi)
#pragma unroll
    for (int fj = 0; fj < 4; ++fj)
#pragma unroll
      for (int r = 0; r < 4; ++r) {
        const int t = w * 32 + fi * 16 + kg * 4 + r;
        const int d = fj * 16 + fr;
        xz[(size_t)(rbase + t) * N2 + h * DH + d] = f2bf(yacc[fi][fj][r]);
      }
  const int dcol = w * 16 + fr;
#pragma unroll
  for (int fi = 0; fi < 4; ++fi) {
    ushort4 pk;
    pk.x = f2bf(hacc[fi][0]); pk.y = f2bf(hacc[fi][1]);
    pk.z = f2bf(hacc[fi][2]); pk.w = f2bf(hacc[fi][3]);
    *(ushort4*)(Hbuf + ((size_t)blk * 64 + dcol) * 64 + fi * 16 + kg * 4) = pk;
  }
}

// ---------------- chunked scan, stage 2: carry across chunks (in place) --------
__global__ __launch_bounds__(256) void k_carry(unsigned short* __restrict__ Hbuf,
                                               const float* __restrict__ Dc) {
  const int bh = blockIdx.x, tid = threadIdx.x;
  float carry[16];
#pragma unroll
  for (int j = 0; j < 16; ++j) carry[j] = 0.f;
  for (int c = 0; c < NCHUNK; ++c) {
    unsigned short* p = Hbuf + (((size_t)(bh * NCHUNK + c)) << 12) + tid * 16;
    const uint4 v0 = *(const uint4*)(p);
    const uint4 v1 = *(const uint4*)(p + 8);
    const unsigned short* hs0 = (const unsigned short*)&v0;
    const unsigned short* hs1 = (const unsigned short*)&v1;
    float hl[16];
#pragma unroll
    for (int j = 0; j < 8; ++j) { hl[j] = bf2f(hs0[j]); hl[8 + j] = bf2f(hs1[j]); }
    uint4 o0, o1;
    unsigned short* os0 = (unsigned short*)&o0;
    unsigned short* os1 = (unsigned short*)&o1;
#pragma unroll
    for (int j = 0; j < 8; ++j) { os0[j] = f2bf(carry[j]); os1[j] = f2bf(carry[8 + j]); }
    *(uint4*)(p) = o0;
    *(uint4*)(p + 8) = o1;
    const float dc = Dc[bh * NCHUNK + c];
#pragma unroll
    for (int j = 0; j < 16; ++j) carry[j] = fmaf(dc, carry[j], hl[j]);
  }
}

// ---------------- chunked scan, stage 3: inter-chunk Y + fused gating ----------
__global__ __launch_bounds__(256) void k_chunk2(
    const unsigned short* __restrict__ Cn, const float* __restrict__ al,
    const unsigned short* __restrict__ Hbuf, const unsigned short* __restrict__ xz,
    unsigned short* __restrict__ xcg) {
  const int blk = blockIdx.x;
  const int bh = blk >> 4, c = blk & 15;
  const int b = bh / NH, h = bh % NH;
  const int tid = threadIdx.x, w = tid >> 6, lane = tid & 63;
  const int fr = lane & 15, kg = lane >> 4;
  const int rbase = b * LLEN + c * QC;
  const size_t bcb = (((size_t)bh << 11) + c * QC) * 64;
  __shared__ float lc[QC];
  __shared__ float wtot[2];
  float a = 1.f, la = 0.f;
  if (tid < QC) { a = al[(size_t)bh * LLEN + c * QC + tid]; la = __logf(a); }
  float s = la;
#pragma unroll
  for (int o = 1; o < 64; o <<= 1) { float t2 = __shfl_up(s, o); if (lane >= o) s += t2; }
  if (tid < QC && lane == 63) wtot[w] = s;
  __syncthreads();
  if (tid < QC) lc[tid] = s + ((w == 1) ? wtot[0] : 0.f);
  __syncthreads();
  bf16x8 cf[2][2];
#pragma unroll
  for (int fi = 0; fi < 2; ++fi) {
    const int t = w * 32 + fi * 16 + fr;
    const float sc = __expf(lc[t]);
#pragma unroll
    for (int kk = 0; kk < 2; ++kk) {
      const uint4 v = *(const uint4*)(Cn + bcb + (size_t)t * 64 + kk * 32 + kg * 8);
      const unsigned short* cs = (const unsigned short*)&v;
      union { unsigned short us[8]; bf16x8 vv; } uv;
#pragma unroll
      for (int q = 0; q < 8; ++q) uv.us[q] = f2bf(bf2f(cs[q]) * sc);
      cf[fi][kk] = uv.vv;
    }
  }
  bf16x8 hf[4][2];
#pragma unroll
  for (int fj = 0; fj < 4; ++fj)
#pragma unroll
    for (int kk = 0; kk < 2; ++kk) {
      const uint4 v = *(const uint4*)(Hbuf + ((size_t)blk * 64 + fj * 16 + fr) * 64 + kk * 32 + kg * 8);
      hf[fj][kk] = *(const bf16x8*)&v;
    }
  f32x4 y[2][4] = {};
#pragma unroll
  for (int kk = 0; kk < 2; ++kk)
#pragma unroll
    for (int fi = 0; fi < 2; ++fi)
#pragma unroll
      for (int fj = 0; fj < 4; ++fj)
        y[fi][fj] = __builtin_amdgcn_mfma_f32_16x16x32_bf16(cf[fi][kk], hf[fj][kk], y[fi][fj], 0, 0, 0);
#pragma unroll
  for (int fi = 0; fi < 2; ++fi)
#pragma unroll
    for (int fj = 0; fj < 4; ++fj)
#pragma unroll
      for (int r = 0; r < 4; ++r) {
        const int t = w * 32 + fi * 16 + kg * 4 + r;
        const int d = fj * 16 + fr;
        const size_t rowg = (size_t)(rbase + t);
        const float yv = y[fi][fj][r] + bf2f(xz[rowg * N2 + h * DH + d]);
        const float zv = bf2f(xz[rowg * N2 + DI + h * DH + d]);
        const float g = yv * (zv / (1.f + __expf(-zv)));
        xcg[rowg * DI + h * DH + d] = f2bf(g);
      }
}

extern "C" void kernel_launch(void* const* d_in, const int* in_sizes, int n_in,
                              void* d_out, int out_size, void* d_ws, size_t ws_size,
                              hipStream_t stream) {
  const float* hs     = (const float*)d_in[0];
  const float* norm_w = (const float*)d_in[1];
  const float* in_w   = (const float*)d_in[2];
  const float* in_b   = (const float*)d_in[3];
  const float* cw     = (const float*)d_in[4];
  const float* cb     = (const float*)d_in[5];
  const float* xw     = (const float*)d_in[6];
  const float* xb     = (const float*)d_in[7];
  const float* A_log  = (const float*)d_in[8];
  const float* l2ab   = (const float*)d_in[9];
  const float* l2b    = (const float*)d_in[10];
  const float* se     = (const float*)d_in[11];
  const float* ow     = (const float*)d_in[12];
  const float* ob     = (const float*)d_in[13];
  const float* rg     = (const float*)d_in[14];
  float* out = (float*)d_out;

  char* ws = (char*)d_ws;
  unsigned short* xnorm = (unsigned short*)(ws);
  unsigned short* wA    = (unsigned short*)(ws + 33554432ull);
  unsigned short* wX    = (unsigned short*)(ws + 46137344ull);
  unsigned short* wO    = (unsigned short*)(ws + 55967744ull);
  unsigned short* xz    = (unsigned short*)(ws + 62259200ull);
  unsigned short* xp    = (unsigned short*)(ws + 112590848ull);
  unsigned short* Bn    = (unsigned short*)(ws + 165019648ull);
  unsigned short* Cn    = (unsigned short*)(ws + 190185472ull);
  unsigned short* xcg   = xnorm;
  unsigned short* Hbuf  = wA;
  float* al             = (float*)(ws + 46137344ull);
  float* Dc             = (float*)(ws + 46137344ull + 786432ull);

  k_w2bf<<<(N2 * DMODEL) / 256, 256, 0, stream>>>(in_w, wA, N2 * DMODEL, N2 * DMODEL);
  k_w2bf<<<(NP_PAD * DI) / 256, 256, 0, stream>>>(xw, wX, NP * DI, NP_PAD * DI);
  k_w2bf<<<(DMODEL * DI) / 256, 256, 0, stream>>>(ow, wO, DMODEL * DI, DMODEL * DI);

  k_rmsnorm<<<MROWS, 256, 0, stream>>>(hs, norm_w, xnorm);
  // in_proj: 128x256 tiles -> 64 x 12 = 768 blocks (exactly 3 rounds), bf16 out
  k_gemm4<<<768, 512, 0, stream>>>(xnorm, wA, in_b, xz, DMODEL, 12, N2, N2);
  k_dwconv<<<(MROWS / 4) * 192 / 256, 256, 0, stream>>>(xz, cw, cb, xcg);
  // x_proj: 256x256 tiles -> 32 x 13 = 416 blocks, bf16 out, ldc 3200
  k_gemm3<1><<<416, 512, 0, stream>>>(xcg, wX, xb, xp, nullptr, nullptr,
                                      DI, 13, NP, NP_PAD);
  k_prep<<<MROWS * 6, 256, 0, stream>>>(xp, xcg, A_log, l2ab, l2b, se, Bn, Cn, al);

  k_chunk1<<<BB * NH * NCHUNK, 256, 0, stream>>>(Bn, Cn, xcg, al, xz, Hbuf, Dc);
  k_carry<<<BB * NH, 256, 0, stream>>>(Hbuf, Dc);
  k_chunk2<<<BB * NH * NCHUNK, 256, 0, stream>>>(Cn, al, Hbuf, xz, xcg);

  // out_proj: 256x256 -> 32 x 8 = 256 blocks (exactly 1 round), fp32 + residual
  k_gemm3<2><<<256, 512, 0, stream>>>(xcg, wO, ob, out, hs, rg,
                                      DI, 8, DMODEL, DMODEL);
}

// Round 9
// 507.043 us; speedup vs baseline: 1.1700x; 1.0339x over previous
//
#include <hip/hip_runtime.h>
#include <stdint.h>

// Problem constants
#define BB 4
#define LLEN 2048
#define DMODEL 2048
#define NH 24
#define DH 64
#define SS 64
#define DI 1536          // NH*DH
#define N2 3072          // 2*DI
#define NP 3096          // NH*(1+2*S)
#define NP_PAD 3200      // weight rows padded (zero rows 3096..3199); also xp ldc
#define MROWS 8192       // BB*LLEN
#define NCHUNK 16
#define QC 128           // chunk length

using bf16x8 = __bf16 __attribute__((ext_vector_type(8)));
using f32x4  = float __attribute__((ext_vector_type(4)));

__device__ __forceinline__ unsigned short f2bf(float f) {
  union { float f; unsigned int u; } v; v.f = f;
  unsigned int u = v.u + 0x7fffu + ((v.u >> 16) & 1u);
  return (unsigned short)(u >> 16);
}
__device__ __forceinline__ float bf2f(unsigned short h) {
  union { unsigned int u; float f; } v; v.u = ((unsigned int)h) << 16;
  return v.f;
}

__device__ __forceinline__ void gload16(const void* g, void* l) {
  __builtin_amdgcn_global_load_lds(
    reinterpret_cast<const __attribute__((address_space(1))) void*>(reinterpret_cast<uintptr_t>(g)),
    reinterpret_cast<__attribute__((address_space(3))) void*>((uint32_t)(reinterpret_cast<uintptr_t>(l))),
    16, 0, 0);
}

// ---------------- fp32 -> bf16 weight convert (with zero row padding) ----------
__global__ __launch_bounds__(256) void k_w2bf(const float* __restrict__ s,
                                              unsigned short* __restrict__ d,
                                              int n_src, int n_dst) {
  int i = blockIdx.x * 256 + threadIdx.x;
  if (i < n_dst) d[i] = (i < n_src) ? f2bf(s[i]) : (unsigned short)0;
}

// ---------------- RMSNorm -> bf16 ----------------
__global__ __launch_bounds__(256) void k_rmsnorm(const float* __restrict__ hs,
                                                 const float* __restrict__ w,
                                                 unsigned short* __restrict__ out) {
  const int row = blockIdx.x;
  const int t = threadIdx.x;
  const float* x = hs + (size_t)row * DMODEL;
  float4 v0 = reinterpret_cast<const float4*>(x)[t * 2 + 0];
  float4 v1 = reinterpret_cast<const float4*>(x)[t * 2 + 1];
  float ss = v0.x * v0.x + v0.y * v0.y + v0.z * v0.z + v0.w * v0.w +
             v1.x * v1.x + v1.y * v1.y + v1.z * v1.z + v1.w * v1.w;
#pragma unroll
  for (int o = 32; o; o >>= 1) ss += __shfl_xor(ss, o);
  __shared__ float red[4];
  if ((t & 63) == 0) red[t >> 6] = ss;
  __syncthreads();
  ss = red[0] + red[1] + red[2] + red[3];
  const float r = rsqrtf(ss * (1.0f / DMODEL) + 1.1920928955078125e-07f);
  float4 w0 = reinterpret_cast<const float4*>(w)[t * 2 + 0];
  float4 w1 = reinterpret_cast<const float4*>(w)[t * 2 + 1];
  union { unsigned short u[8]; uint4 v; } pk;
  pk.u[0] = f2bf(v0.x * r * w0.x); pk.u[1] = f2bf(v0.y * r * w0.y);
  pk.u[2] = f2bf(v0.z * r * w0.z); pk.u[3] = f2bf(v0.w * r * w0.w);
  pk.u[4] = f2bf(v1.x * r * w1.x); pk.u[5] = f2bf(v1.y * r * w1.y);
  pk.u[6] = f2bf(v1.z * r * w1.z); pk.u[7] = f2bf(v1.w * r * w1.w);
  *reinterpret_cast<uint4*>(out + (size_t)row * DMODEL + t * 8) = pk.v;
}

// ---------------- drift-scheduled bf16 NT GEMM (BMH x 256 tile, BK=64) ---------
// ONE barrier per K-tile; no per-phase barriers -> waves drift so one wave's
// ds_reads overlap another's MFMA (the lockstep serialization was the 35% cap).
// EPI 1: bf16 C = acc+bias. EPI 2: fp32 C = resid + rg*(acc+bias).
// 512 thr = 8 waves (2M x 4N). BMH=128: per-wave 64x64, LDS 96KB.
// BMH=256: per-wave 128x64, LDS 128KB (two read/MFMA groups to cap VGPR).
template <int EPI, int BMH>
__global__ __launch_bounds__(512, 2)
void k_gemm5(const unsigned short* __restrict__ A, const unsigned short* __restrict__ B,
             const float* __restrict__ bias, void* __restrict__ Cv,
             const float* __restrict__ resid, const float* __restrict__ gatep,
             int K, int NT_N, int Nout, int ldc) {
  constexpr int NSET = BMH / 64;        // A frag-set pairs per wave (2 or 4 frags->/2)
  constexpr int AELEM = BMH * 64;       // A elements per buffer
  constexpr int BUFE = AELEM + 16384;   // elements per buffer (B = 256x64)
  __shared__ alignas(16) unsigned short sm[2 * BUFE];
  const int tid = threadIdx.x;
  const int lane = tid & 63, wid = tid >> 6;
  const int wm = wid >> 2, wn = wid & 3;
  const int fr = lane & 15, kg = lane >> 4;
  const int nwg = gridDim.x;
  const int wg = ((int)blockIdx.x & 7) * (nwg >> 3) + ((int)blockIdx.x >> 3);
  const int m0 = (wg / NT_N) * BMH, n0 = (wg % NT_N) * 256;
  const int NT = K >> 6;

  // pre-swizzled per-lane global staging sources (granule q ^= row&7)
  const unsigned short* asrc[NSET];
  const unsigned short* bsrc[4];
#pragma unroll
  for (int li = 0; li < NSET; ++li) {
    const int gi = li * 512 + tid, r = gi >> 3, q = gi & 7;
    asrc[li] = A + (size_t)(m0 + r) * K + ((q ^ (r & 7)) << 3);
  }
#pragma unroll
  for (int li = 0; li < 4; ++li) {
    const int gi = li * 512 + tid, r = gi >> 3, q = gi & 7;
    bsrc[li] = B + (size_t)(n0 + r) * K + ((q ^ (r & 7)) << 3);
  }
  const int wlds = wid * 64;

#define STG5(buf, ko)                                                          \
  { unsigned short* da_ = sm + (buf) * BUFE;                                   \
    _Pragma("unroll") for (int li = 0; li < NSET; ++li)                        \
      gload16(asrc[li] + (ko), da_ + ((li * 512 + wlds) << 3));                \
    unsigned short* db_ = sm + (buf) * BUFE + AELEM;                           \
    _Pragma("unroll") for (int li = 0; li < 4; ++li)                           \
      gload16(bsrc[li] + (ko), db_ + ((li * 512 + wlds) << 3)); }

#define ARD5(bufp, f, kk)                                                      \
  (*(const bf16x8*)((bufp) +                                                   \
      (((f) < 4 ? wm * 64 + (f) * 16 : 128 + wm * 64 + ((f) - 4) * 16) + fr) * 64 + \
      ((((kk) * 4 + kg) ^ (fr & 7)) << 3)))
#define BRD5(bufp, nf, kk)                                                     \
  (*(const bf16x8*)((bufp) + AELEM + (wn * 64 + (nf) * 16 + fr) * 64 +         \
      ((((kk) * 4 + kg) ^ (fr & 7)) << 3)))

  f32x4 acc[2 * NSET][4] = {};

  // prologue: stage tile 0, drain, barrier
  STG5(0, 0)
  asm volatile("s_waitcnt vmcnt(0)" ::: "memory");
  __builtin_amdgcn_s_barrier();

  for (int t = 0; t < NT; ++t) {
    unsigned short* bc = sm + (t & 1) * BUFE;
    if (t + 1 < NT) STG5((t & 1) ^ 1, (t + 1) << 6)

    // group 0: B(all) + A frags 0..3
    bf16x8 bfv[4][2], af[2][2][2];
#pragma unroll
    for (int nf = 0; nf < 4; ++nf) {
      bfv[nf][0] = BRD5(bc, nf, 0);
      bfv[nf][1] = BRD5(bc, nf, 1);
    }
#pragma unroll
    for (int s = 0; s < 2; ++s)
#pragma unroll
      for (int mf = 0; mf < 2; ++mf)
#pragma unroll
        for (int kk = 0; kk < 2; ++kk)
          af[s][mf][kk] = ARD5(bc, s * 2 + mf, kk);
    __builtin_amdgcn_sched_barrier(0);
    asm volatile("s_waitcnt lgkmcnt(0)" ::: "memory");
    __builtin_amdgcn_sched_barrier(0);
    __builtin_amdgcn_s_setprio(1);
#pragma unroll
    for (int s = 0; s < 2; ++s)
#pragma unroll
      for (int mf = 0; mf < 2; ++mf)
#pragma unroll
        for (int nf = 0; nf < 4; ++nf)
#pragma unroll
          for (int kk = 0; kk < 2; ++kk)
            acc[s * 2 + mf][nf] = __builtin_amdgcn_mfma_f32_16x16x32_bf16(
                af[s][mf][kk], bfv[nf][kk], acc[s * 2 + mf][nf], 0, 0, 0);
    __builtin_amdgcn_s_setprio(0);

    if (NSET == 4) {
      // group 1: A frags 4..7 (rows 128+)
      bf16x8 ag[2][2][2];
#pragma unroll
      for (int s = 0; s < 2; ++s)
#pragma unroll
        for (int mf = 0; mf < 2; ++mf)
#pragma unroll
          for (int kk = 0; kk < 2; ++kk)
            ag[s][mf][kk] = ARD5(bc, 4 + s * 2 + mf, kk);
      __builtin_amdgcn_sched_barrier(0);
      asm volatile("s_waitcnt lgkmcnt(0)" ::: "memory");
      __builtin_amdgcn_sched_barrier(0);
      __builtin_amdgcn_s_setprio(1);
#pragma unroll
      for (int s = 0; s < 2; ++s)
#pragma unroll
        for (int mf = 0; mf < 2; ++mf)
#pragma unroll
          for (int nf = 0; nf < 4; ++nf)
#pragma unroll
            for (int kk = 0; kk < 2; ++kk)
              acc[4 + s * 2 + mf][nf] = __builtin_amdgcn_mfma_f32_16x16x32_bf16(
                  ag[s][mf][kk], bfv[nf][kk], acc[4 + s * 2 + mf][nf], 0, 0, 0);
      __builtin_amdgcn_s_setprio(0);
    }

    // tile boundary: next tile's staging must be resident; all LDS reads retired
    asm volatile("s_waitcnt vmcnt(0)" ::: "memory");
    __builtin_amdgcn_s_barrier();
  }

  // epilogue
  float* Cf = (float*)Cv;
  unsigned short* Ch = (unsigned short*)Cv;
  const float rg = (EPI == 2) ? gatep[0] : 0.f;
#pragma unroll
  for (int nf = 0; nf < 4; ++nf) {
    const int col = n0 + wn * 64 + nf * 16 + fr;
    if (col >= Nout) continue;
    const float bv = bias[col];
#pragma unroll
    for (int mf = 0; mf < 2 * NSET; ++mf) {
      const int rowb = m0 + ((mf < 4) ? wm * 64 + mf * 16
                                      : 128 + wm * 64 + (mf - 4) * 16) + kg * 4;
#pragma unroll
      for (int r = 0; r < 4; ++r) {
        const size_t o = (size_t)(rowb + r) * ldc + col;
        float v = acc[mf][nf][r] + bv;
        if (EPI == 1) {
          Ch[o] = f2bf(v);
        } else {
          if (EPI == 2) v = resid[o] + rg * v;
          Cf[o] = v;
        }
      }
    }
  }
#undef STG5
#undef ARD5
#undef BRD5
}

// ---------------- depthwise causal conv(4) + silu, 4 timesteps x 8 ch/thread ---
__global__ __launch_bounds__(256) void k_dwconv(const unsigned short* __restrict__ xz,
                                                const float* __restrict__ cw,
                                                const float* __restrict__ cb,
                                                unsigned short* __restrict__ out) {
  const int idx = blockIdx.x * 256 + threadIdx.x;  // < (MROWS/4)*192
  const int c0 = (idx % 192) * 8;
  const int bl0 = (idx / 192) * 4;
  const int lpos0 = bl0 & (LLEN - 1);
  float w[8][4];
#pragma unroll
  for (int j = 0; j < 8; ++j) {
    const float4 wv = *(const float4*)(cw + (c0 + j) * 4);
    w[j][0] = wv.x; w[j][1] = wv.y; w[j][2] = wv.z; w[j][3] = wv.w;
  }
  float xr[7][8];
#pragma unroll
  for (int m = 0; m < 7; ++m) {
    uint4 xv = make_uint4(0u, 0u, 0u, 0u);
    if (lpos0 - 3 + m >= 0)
      xv = *(const uint4*)(xz + (size_t)(bl0 - 3 + m) * N2 + c0);
    const unsigned short* xs = (const unsigned short*)&xv;
#pragma unroll
    for (int j = 0; j < 8; ++j) xr[m][j] = bf2f(xs[j]);
  }
  const float4 cb0 = *(const float4*)(cb + c0);
  const float4 cb1 = *(const float4*)(cb + c0 + 4);
  const float cbv[8] = {cb0.x, cb0.y, cb0.z, cb0.w, cb1.x, cb1.y, cb1.z, cb1.w};
#pragma unroll
  for (int t4 = 0; t4 < 4; ++t4) {
    union { unsigned short u[8]; uint4 v; } pk;
#pragma unroll
    for (int j = 0; j < 8; ++j) {
      float a = cbv[j];
#pragma unroll
      for (int k = 0; k < 4; ++k) a = fmaf(w[j][k], xr[t4 + k][j], a);
      a = a / (1.f + __expf(-a));
      pk.u[j] = f2bf(a);
    }
    *(uint4*)(out + (size_t)(bl0 + t4) * DI + c0) = pk.v;
  }
}

// ---------------- prep: read bf16 xp, write normalized B/C to Bn/Cn, alpha -----
__global__ __launch_bounds__(256) void k_prep(const unsigned short* __restrict__ xp,
                                              const unsigned short* __restrict__ xc,
                                              const float* __restrict__ A_log,
                                              const float* __restrict__ l2ab,
                                              const float* __restrict__ l2b,
                                              const float* __restrict__ se,
                                              unsigned short* __restrict__ Bn,
                                              unsigned short* __restrict__ Cn,
                                              float* __restrict__ al) {
  const int blk = blockIdx.x;               // MROWS*6
  const int w = threadIdx.x >> 6, lane = threadIdx.x & 63;
  const int bl = blk / 6, hq = blk % 6;
  const int h = hq * 4 + w;
  const size_t pbase = (size_t)bl * NP_PAD + h * 129;
  const float bs = bf2f(xp[pbase + 1 + lane]);
  const float cs = bf2f(xp[pbase + 65 + lane]);
  const float xv = bf2f(xc[(size_t)bl * DI + h * DH + lane]);
  float sb = bs * bs, sc = cs * cs, sx = xv;
#pragma unroll
  for (int o = 32; o; o >>= 1) {
    sb += __shfl_xor(sb, o);
    sc += __shfl_xor(sc, o);
    sx += __shfl_xor(sx, o);
  }
  const float nb = fmaxf(sqrtf(sb), 1e-12f);
  const float nc = fmaxf(sqrtf(sc), 1e-12f);
  const int b = bl >> 11, l = bl & (LLEN - 1);
  const size_t ob = (((size_t)(b * NH + h) << 11) + l) * 64 + lane;
  Bn[ob] = f2bf(bs / nb);
  Cn[ob] = f2bf(cs / nc);
  const float sumB2 = sb / (nb * nb);
  const float xmean = sx * (1.f / 64.f);
  const float dt = bf2f(xp[pbase]);
  const float sp = (dt > 20.f) ? dt : log1pf(expf(dt));
  const float Ac = fminf(fmaxf(A_log[h], -2.3f), -0.01f);
  const float aa = expf(Ac * sp);
  const float one_a = 1.f - aa;
  const float pe = one_a * one_a * xmean * xmean * sumB2 * (1.f / 64.f);
  const float ns = pe / (se[h] + 1e-6f);
  const float beta = exp2f(fminf(fmaxf(l2b[h], -2.f), 2.f));
  const float boost = fmaxf(tanhf(beta * ns), 0.f);
  const float ab = 1.f - exp2f(fminf(fmaxf(l2ab[h], -3.32f), -0.015f));
  const float alpha = fminf(fmaxf(ab + (1.f - ab) * boost, 0.01f), 0.999f);
  if (lane == 0) al[(((size_t)b * NH + h) << 11) + l] = alpha;
}

// ---------------- chunked scan, stage 1: intra-chunk Y + local state -----------
__global__ __launch_bounds__(256) void k_chunk1(
    const unsigned short* __restrict__ Bn, const unsigned short* __restrict__ Cn,
    const unsigned short* __restrict__ xcg, const float* __restrict__ al,
    unsigned short* __restrict__ xz, unsigned short* __restrict__ Hbuf,
    float* __restrict__ Dc) {
  const int blk = blockIdx.x;          // bh*16 + c
  const int bh = blk >> 4, c = blk & 15;
  const int b = bh / NH, h = bh % NH;
  const int tid = threadIdx.x, w = tid >> 6, lane = tid & 63;
  const int fr = lane & 15, kg = lane >> 4;
  const int rbase = b * LLEN + c * QC;
  const size_t bcb = (((size_t)bh << 11) + c * QC) * 64;  // Bn/Cn base

  __shared__ float lc[QC], ia[QC], escl[QC];
  __shared__ float wtot[2];
  __shared__ alignas(16) unsigned short XT[64][152];   // [d][u]
  __shared__ alignas(16) unsigned short BsT[64][152];  // [s][u] (scaled)
  __shared__ alignas(16) unsigned short Pt[128][88];   // [t][u-local]

  float a = 1.f, la = 0.f;
  if (tid < QC) { a = al[(size_t)bh * LLEN + c * QC + tid]; la = __logf(a); }
  float s = la;
#pragma unroll
  for (int o = 1; o < 64; o <<= 1) { float t2 = __shfl_up(s, o); if (lane >= o) s += t2; }
  if (tid < QC && lane == 63) wtot[w] = s;
  __syncthreads();
  if (tid < QC) { lc[tid] = s + ((w == 1) ? wtot[0] : 0.f); ia[tid] = 1.f - a; }
  __syncthreads();
  const float lcE = lc[QC - 1];
  if (tid < QC) escl[tid] = __expf(lcE - lc[tid]) * ia[tid];
  if (tid == 0) Dc[blk] = __expf(lcE);
  __syncthreads();

  {
    const int r8 = tid >> 3, q8 = tid & 7;
#pragma unroll
    for (int it = 0; it < 4; ++it) {
      const int u = it * 32 + r8;
      const uint4 xv = *(const uint4*)(xcg + (size_t)(rbase + u) * DI + h * DH + q8 * 8);
      const unsigned short* xs = (const unsigned short*)&xv;
#pragma unroll
      for (int j = 0; j < 8; ++j) XT[q8 * 8 + j][u] = xs[j];
      const uint4 bv = *(const uint4*)(Bn + bcb + (size_t)u * 64 + q8 * 8);
      const unsigned short* bsv = (const unsigned short*)&bv;
      const float e = escl[u];
#pragma unroll
      for (int j = 0; j < 8; ++j) BsT[q8 * 8 + j][u] = f2bf(bf2f(bsv[j]) * e);
    }
  }
  bf16x8 cf[2][2];
#pragma unroll
  for (int fi = 0; fi < 2; ++fi)
#pragma unroll
    for (int kk = 0; kk < 2; ++kk) {
      const int t = w * 32 + fi * 16 + fr;
      const uint4 v = *(const uint4*)(Cn + bcb + (size_t)t * 64 + kk * 32 + kg * 8);
      cf[fi][kk] = *(const bf16x8*)&v;
    }
  __syncthreads();

  float lct[2][4];
#pragma unroll
  for (int fi = 0; fi < 2; ++fi)
#pragma unroll
    for (int r = 0; r < 4; ++r) lct[fi][r] = lc[w * 32 + fi * 16 + kg * 4 + r];

  f32x4 yacc[2][4] = {};
  f32x4 hacc[4] = {};
#pragma unroll
  for (int ut = 0; ut < 2; ++ut) {
    f32x4 g[2][4] = {};
#pragma unroll
    for (int kk = 0; kk < 2; ++kk)
#pragma unroll
      for (int fj = 0; fj < 4; ++fj) {
        const int u = ut * 64 + fj * 16 + fr;
        const uint4 v = *(const uint4*)(Bn + bcb + (size_t)u * 64 + kk * 32 + kg * 8);
        const bf16x8 bfrag = *(const bf16x8*)&v;
#pragma unroll
        for (int fi = 0; fi < 2; ++fi)
          g[fi][fj] = __builtin_amdgcn_mfma_f32_16x16x32_bf16(cf[fi][kk], bfrag, g[fi][fj], 0, 0, 0);
      }
#pragma unroll
    for (int fi = 0; fi < 2; ++fi)
#pragma unroll
      for (int fj = 0; fj < 4; ++fj) {
        const int u = ut * 64 + fj * 16 + fr;
        const float lcu = lc[u], iau = ia[u];
#pragma unroll
        for (int r = 0; r < 4; ++r) {
          const int t = w * 32 + fi * 16 + kg * 4 + r;
          const float v = (t >= u) ? g[fi][fj][r] * __expf(lct[fi][r] - lcu) * iau : 0.f;
          Pt[t][fj * 16 + fr] = f2bf(v);
        }
      }
#pragma unroll
    for (int kk = 0; kk < 2; ++kk) {
      bf16x8 xf[4];
#pragma unroll
      for (int fj = 0; fj < 4; ++fj)
        xf[fj] = *(const bf16x8*)&XT[fj * 16 + fr][ut * 64 + kk * 32 + kg * 8];
      bf16x8 pf[2];
#pragma unroll
      for (int fi = 0; fi < 2; ++fi)
        pf[fi] = *(const bf16x8*)&Pt[w * 32 + fi * 16 + fr][kk * 32 + kg * 8];
#pragma unroll
      for (int fi = 0; fi < 2; ++fi)
#pragma unroll
        for (int fj = 0; fj < 4; ++fj)
          yacc[fi][fj] = __builtin_amdgcn_mfma_f32_16x16x32_bf16(pf[fi], xf[fj], yacc[fi][fj], 0, 0, 0);
      const bf16x8 xh = *(const bf16x8*)&XT[w * 16 + fr][ut * 64 + kk * 32 + kg * 8];
#pragma unroll
      for (int fi = 0; fi < 4; ++fi) {
        const bf16x8 bs = *(const bf16x8*)&BsT[fi * 16 + fr][ut * 64 + kk * 32 + kg * 8];
        hacc[fi] = __builtin_amdgcn_mfma_f32_16x16x32_bf16(bs, xh, hacc[fi], 0, 0, 0);
      }
    }
  }
#pragma unroll
  for (int fi = 0; fi < 2; ++fi)
#pragma unroll
    for (int fj = 0; fj < 4; ++fj)
#pragma unroll
      for (int r = 0; r < 4; ++r) {
        const int t = w * 32 + fi * 16 + kg * 4 + r;
        const int d = fj * 16 + fr;
        xz[(size_t)(rbase + t) * N2 + h * DH + d] = f2bf(yacc[fi][fj][r]);
      }
  const int dcol = w * 16 + fr;
#pragma unroll
  for (int fi = 0; fi < 4; ++fi) {
    ushort4 pk;
    pk.x = f2bf(hacc[fi][0]); pk.y = f2bf(hacc[fi][1]);
    pk.z = f2bf(hacc[fi][2]); pk.w = f2bf(hacc[fi][3]);
    *(ushort4*)(Hbuf + ((size_t)blk * 64 + dcol) * 64 + fi * 16 + kg * 4) = pk;
  }
}

// ---------------- chunked scan, stage 2: carry across chunks (in place) --------
__global__ __launch_bounds__(256) void k_carry(unsigned short* __restrict__ Hbuf,
                                               const float* __restrict__ Dc) {
  const int bh = blockIdx.x, tid = threadIdx.x;
  float carry[16];
#pragma unroll
  for (int j = 0; j < 16; ++j) carry[j] = 0.f;
  for (int c = 0; c < NCHUNK; ++c) {
    unsigned short* p = Hbuf + (((size_t)(bh * NCHUNK + c)) << 12) + tid * 16;
    const uint4 v0 = *(const uint4*)(p);
    const uint4 v1 = *(const uint4*)(p + 8);
    const unsigned short* hs0 = (const unsigned short*)&v0;
    const unsigned short* hs1 = (const unsigned short*)&v1;
    float hl[16];
#pragma unroll
    for (int j = 0; j < 8; ++j) { hl[j] = bf2f(hs0[j]); hl[8 + j] = bf2f(hs1[j]); }
    uint4 o0, o1;
    unsigned short* os0 = (unsigned short*)&o0;
    unsigned short* os1 = (unsigned short*)&o1;
#pragma unroll
    for (int j = 0; j < 8; ++j) { os0[j] = f2bf(carry[j]); os1[j] = f2bf(carry[8 + j]); }
    *(uint4*)(p) = o0;
    *(uint4*)(p + 8) = o1;
    const float dc = Dc[bh * NCHUNK + c];
#pragma unroll
    for (int j = 0; j < 16; ++j) carry[j] = fmaf(dc, carry[j], hl[j]);
  }
}

// ---------------- chunked scan, stage 3: inter-chunk Y + fused gating ----------
__global__ __launch_bounds__(256) void k_chunk2(
    const unsigned short* __restrict__ Cn, const float* __restrict__ al,
    const unsigned short* __restrict__ Hbuf, const unsigned short* __restrict__ xz,
    unsigned short* __restrict__ xcg) {
  const int blk = blockIdx.x;
  const int bh = blk >> 4, c = blk & 15;
  const int b = bh / NH, h = bh % NH;
  const int tid = threadIdx.x, w = tid >> 6, lane = tid & 63;
  const int fr = lane & 15, kg = lane >> 4;
  const int rbase = b * LLEN + c * QC;
  const size_t bcb = (((size_t)bh << 11) + c * QC) * 64;
  __shared__ float lc[QC];
  __shared__ float wtot[2];
  float a = 1.f, la = 0.f;
  if (tid < QC) { a = al[(size_t)bh * LLEN + c * QC + tid]; la = __logf(a); }
  float s = la;
#pragma unroll
  for (int o = 1; o < 64; o <<= 1) { float t2 = __shfl_up(s, o); if (lane >= o) s += t2; }
  if (tid < QC && lane == 63) wtot[w] = s;
  __syncthreads();
  if (tid < QC) lc[tid] = s + ((w == 1) ? wtot[0] : 0.f);
  __syncthreads();
  bf16x8 cf[2][2];
#pragma unroll
  for (int fi = 0; fi < 2; ++fi) {
    const int t = w * 32 + fi * 16 + fr;
    const float sc = __expf(lc[t]);
#pragma unroll
    for (int kk = 0; kk < 2; ++kk) {
      const uint4 v = *(const uint4*)(Cn + bcb + (size_t)t * 64 + kk * 32 + kg * 8);
      const unsigned short* cs = (const unsigned short*)&v;
      union { unsigned short us[8]; bf16x8 vv; } uv;
#pragma unroll
      for (int q = 0; q < 8; ++q) uv.us[q] = f2bf(bf2f(cs[q]) * sc);
      cf[fi][kk] = uv.vv;
    }
  }
  bf16x8 hf[4][2];
#pragma unroll
  for (int fj = 0; fj < 4; ++fj)
#pragma unroll
    for (int kk = 0; kk < 2; ++kk) {
      const uint4 v = *(const uint4*)(Hbuf + ((size_t)blk * 64 + fj * 16 + fr) * 64 + kk * 32 + kg * 8);
      hf[fj][kk] = *(const bf16x8*)&v;
    }
  f32x4 y[2][4] = {};
#pragma unroll
  for (int kk = 0; kk < 2; ++kk)
#pragma unroll
    for (int fi = 0; fi < 2; ++fi)
#pragma unroll
      for (int fj = 0; fj < 4; ++fj)
        y[fi][fj] = __builtin_amdgcn_mfma_f32_16x16x32_bf16(cf[fi][kk], hf[fj][kk], y[fi][fj], 0, 0, 0);
#pragma unroll
  for (int fi = 0; fi < 2; ++fi)
#pragma unroll
    for (int fj = 0; fj < 4; ++fj)
#pragma unroll
      for (int r = 0; r < 4; ++r) {
        const int t = w * 32 + fi * 16 + kg * 4 + r;
        const int d = fj * 16 + fr;
        const size_t rowg = (size_t)(rbase + t);
        const float yv = y[fi][fj][r] + bf2f(xz[rowg * N2 + h * DH + d]);
        const float zv = bf2f(xz[rowg * N2 + DI + h * DH + d]);
        const float g = yv * (zv / (1.f + __expf(-zv)));
        xcg[rowg * DI + h * DH + d] = f2bf(g);
      }
}

extern "C" void kernel_launch(void* const* d_in, const int* in_sizes, int n_in,
                              void* d_out, int out_size, void* d_ws, size_t ws_size,
                              hipStream_t stream) {
  const float* hs     = (const float*)d_in[0];
  const float* norm_w = (const float*)d_in[1];
  const float* in_w   = (const float*)d_in[2];
  const float* in_b   = (const float*)d_in[3];
  const float* cw     = (const float*)d_in[4];
  const float* cb     = (const float*)d_in[5];
  const float* xw     = (const float*)d_in[6];
  const float* xb     = (const float*)d_in[7];
  const float* A_log  = (const float*)d_in[8];
  const float* l2ab   = (const float*)d_in[9];
  const float* l2b    = (const float*)d_in[10];
  const float* se     = (const float*)d_in[11];
  const float* ow     = (const float*)d_in[12];
  const float* ob     = (const float*)d_in[13];
  const float* rg     = (const float*)d_in[14];
  float* out = (float*)d_out;

  char* ws = (char*)d_ws;
  unsigned short* xnorm = (unsigned short*)(ws);
  unsigned short* wA    = (unsigned short*)(ws + 33554432ull);
  unsigned short* wX    = (unsigned short*)(ws + 46137344ull);
  unsigned short* wO    = (unsigned short*)(ws + 55967744ull);
  unsigned short* xz    = (unsigned short*)(ws + 62259200ull);
  unsigned short* xp    = (unsigned short*)(ws + 112590848ull);
  unsigned short* Bn    = (unsigned short*)(ws + 165019648ull);
  unsigned short* Cn    = (unsigned short*)(ws + 190185472ull);
  unsigned short* xcg   = xnorm;
  unsigned short* Hbuf  = wA;
  float* al             = (float*)(ws + 46137344ull);
  float* Dc             = (float*)(ws + 46137344ull + 786432ull);

  k_w2bf<<<(N2 * DMODEL) / 256, 256, 0, stream>>>(in_w, wA, N2 * DMODEL, N2 * DMODEL);
  k_w2bf<<<(NP_PAD * DI) / 256, 256, 0, stream>>>(xw, wX, NP * DI, NP_PAD * DI);
  k_w2bf<<<(DMODEL * DI) / 256, 256, 0, stream>>>(ow, wO, DMODEL * DI, DMODEL * DI);

  k_rmsnorm<<<MROWS, 256, 0, stream>>>(hs, norm_w, xnorm);
  // in_proj: 128x256 tiles -> 64 x 12 = 768 blocks (exactly 3 rounds), bf16 out
  k_gemm5<1, 128><<<768, 512, 0, stream>>>(xnorm, wA, in_b, xz, nullptr, nullptr,
                                           DMODEL, 12, N2, N2);
  k_dwconv<<<(MROWS / 4) * 192 / 256, 256, 0, stream>>>(xz, cw, cb, xcg);
  // x_proj: 256x256 tiles -> 32 x 13 = 416 blocks, bf16 out, ldc 3200
  k_gemm5<1, 256><<<416, 512, 0, stream>>>(xcg, wX, xb, xp, nullptr, nullptr,
                                           DI, 13, NP, NP_PAD);
  k_prep<<<MROWS * 6, 256, 0, stream>>>(xp, xcg, A_log, l2ab, l2b, se, Bn, Cn, al);

  k_chunk1<<<BB * NH * NCHUNK, 256, 0, stream>>>(Bn, Cn, xcg, al, xz, Hbuf, Dc);
  k_carry<<<BB * NH, 256, 0, stream>>>(Hbuf, Dc);
  k_chunk2<<<BB * NH * NCHUNK, 256, 0, stream>>>(Cn, al, Hbuf, xz, xcg);

  // out_proj: 256x256 -> 32 x 8 = 256 blocks (exactly 1 round), fp32 + residual
  k_gemm5<2, 256><<<256, 512, 0, stream>>>(xcg, wO, ob, out, hs, rg,
                                           DI, 8, DMODEL, DMODEL);
}